// Round 7
// baseline (1043.422 us; speedup 1.0000x reference)
//
#include <hip/hip_runtime.h>
#include <hip/hip_bf16.h>

// ---------------------------------------------------------------------------
// ERCGNN R6 (resubmit after infra failure): interleaved gather matrices
// (G2: fbf+hnL0 -> dwordx2/edge; G4: hnL1+y0u/p/f -> dwordx4/edge), GAT
// BN-stats fused into gather epilogue, batched GCN classifiers.
// ---------------------------------------------------------------------------

#define NN 50000
#define NE 500000
#define DD 128
#define NH 8
#define DHD 16
#define NCLS 7
#define SCAN_B 196  // ceil(50000/256)

typedef __attribute__((ext_vector_type(8))) short short8;
typedef __attribute__((ext_vector_type(4))) float f32x4;

__device__ __forceinline__ unsigned short f2bf(float x) {
    unsigned int u = __float_as_uint(x);
    unsigned int r = (u + 0x7fffu + ((u >> 16) & 1u)) >> 16;  // RNE
    return (unsigned short)r;
}
__device__ __forceinline__ unsigned int pack2bf(float lo, float hi) {
    return (unsigned int)f2bf(lo) | ((unsigned int)f2bf(hi) << 16);
}
__device__ __forceinline__ float bflo(unsigned int u) { return __uint_as_float(u << 16); }
__device__ __forceinline__ float bfhi(unsigned int u) { return __uint_as_float(u & 0xffff0000u); }

// ---------------- CSR build ----------------

__global__ void count_kernel(const int* __restrict__ row, int* __restrict__ cnt) {
    int e = blockIdx.x * 256 + threadIdx.x;
    if (e < NE) atomicAdd(&cnt[row[e]], 1);
}

__global__ __launch_bounds__(256) void scan1_kernel(const int* __restrict__ cnt,
                                                    int* __restrict__ pre,
                                                    int* __restrict__ bsum) {
    __shared__ int s[256];
    int t = threadIdx.x;
    int i = blockIdx.x * 256 + t;
    int v = (i < NN) ? cnt[i] : 0;
    s[t] = v;
    __syncthreads();
    for (int off = 1; off < 256; off <<= 1) {
        int u = (t >= off) ? s[t - off] : 0;
        __syncthreads();
        s[t] += u;
        __syncthreads();
    }
    if (i < NN) pre[i] = s[t] - v;
    if (t == 255) bsum[blockIdx.x] = s[255];
}

__global__ __launch_bounds__(256) void scan2_kernel(const int* __restrict__ bsum,
                                                    int* __restrict__ boff) {
    __shared__ int s[256];
    int t = threadIdx.x;
    int v = (t < SCAN_B) ? bsum[t] : 0;
    s[t] = v;
    __syncthreads();
    for (int off = 1; off < 256; off <<= 1) {
        int u = (t >= off) ? s[t - off] : 0;
        __syncthreads();
        s[t] += u;
        __syncthreads();
    }
    boff[t] = s[t] - v;
    if (t == 255) boff[256] = s[255];
}

__global__ __launch_bounds__(256) void scan3_kernel(const int* __restrict__ pre,
                                                    const int* __restrict__ boff,
                                                    int* __restrict__ row_ptr,
                                                    int* __restrict__ fill) {
    int t = threadIdx.x;
    int i = blockIdx.x * 256 + t;
    if (i < NN) {
        int v = pre[i] + boff[blockIdx.x];
        row_ptr[i] = v;
        fill[i] = v;
    }
    if (blockIdx.x == 0 && t == 0) row_ptr[NN] = boff[256];
}

// 32B edge record: {col, vg, vu, vp} {vf, 0, 0, 0}
__global__ void scatter_kernel(const int* __restrict__ row, const int* __restrict__ col,
                               const float* __restrict__ vg, const float* __restrict__ vu,
                               const float* __restrict__ vp, const float* __restrict__ vf,
                               int* __restrict__ fill, int4* __restrict__ ed) {
    int e = blockIdx.x * 256 + threadIdx.x;
    if (e >= NE) return;
    int r = row[e];
    int pos = atomicAdd(&fill[r], 1);
    ed[2 * pos] = make_int4(col[e], __float_as_int(vg[e]), __float_as_int(vu[e]),
                            __float_as_int(vp[e]));
    ed[2 * pos + 1] = make_int4(__float_as_int(vf[e]), 0, 0, 0);
}

// ---------------- fp32 -> bf16 (plain fbf + G2 slice 0) ----------------

__global__ __launch_bounds__(256) void tobf16_kernel(const float* __restrict__ x,
                                                     short* __restrict__ y,
                                                     char* __restrict__ G2) {
    int idx = blockIdx.x * 256 + threadIdx.x;  // 8 feats each
    if (idx >= NN * DD / 8) return;
    int node = idx >> 4;
    int k0 = (idx & 15) * 8;
    float4 a = ((const float4*)x)[idx * 2];
    float4 b = ((const float4*)x)[idx * 2 + 1];
    uint4 o;
    o.x = pack2bf(a.x, a.y);
    o.y = pack2bf(a.z, a.w);
    o.z = pack2bf(b.x, b.y);
    o.w = pack2bf(b.z, b.w);
    *(uint4*)(y + (size_t)idx * 8) = o;
    char* g = G2 + (size_t)node * 512 + (k0 >> 1) * 8;
    *(unsigned int*)(g) = o.x;
    *(unsigned int*)(g + 8) = o.y;
    *(unsigned int*)(g + 16) = o.z;
    *(unsigned int*)(g + 24) = o.w;
}

// ---------------- weight prep ----------------

struct WPrepArgs {
    const float* src[11];
};

__global__ __launch_bounds__(256) void wprep_kernel(WPrepArgs a, short* __restrict__ out) {
    int idx = blockIdx.x * 256 + threadIdx.x;
    if (idx >= 11 * DD * DD) return;
    int w = idx >> 14;
    int r = idx & 16383;
    int n = r >> 7, k = r & 127;
    const float* W = a.src[w];
    float v = (w < 4) ? W[(size_t)((n >> 4) * DD + k) * DHD + (n & 15)] : W[(size_t)k * DD + n];
    out[idx] = (short)f2bf(v);
}

// ---- wfix: fold BN(y0) into L1 weights ----

struct WFixArgs {
    const float* W1[3];
    const float* b1[3];
    const float* stats[3];
};

__global__ __launch_bounds__(256) void wfix_kernel(WFixArgs a, short* __restrict__ wt_out,
                                                   float* __restrict__ bfix) {
    int idx = blockIdx.x * 256 + threadIdx.x;
    if (idx >= 3 * DD) return;
    int br = idx >> 7, n = idx & 127;
    const float* st = a.stats[br];
    const float* W = a.W1[br];
    const float inv_n = 1.0f / (float)NN;
    float accb = 0.f;
    short* wo = wt_out + (size_t)br * DD * DD + (size_t)n * DD;
#pragma unroll 4
    for (int k = 0; k < DD; ++k) {
        float m = st[k] * inv_n;
        float var = st[DD + k] * inv_n - m * m;
        float s = rsqrtf(var + 1e-9f);
        float w = W[(size_t)k * DD + n];
        wo[k] = (short)f2bf(s * w);
        accb += m * s * w;
    }
    bfix[idx] = a.b1[br][n] - accb;
}

// ---------------- self matmul: bf16 A -> fp32 relu C, stats ----------------

__global__ __launch_bounds__(256) void mfma_mm_self(const short* __restrict__ A,
                                                    const short* __restrict__ Wt,
                                                    const float* __restrict__ bias,
                                                    float* __restrict__ stats_out,
                                                    float* __restrict__ C) {
    __shared__ short As[64 * DD];
    int t = threadIdx.x;
    int r0 = blockIdx.x * 64;
    {
        int srow = t >> 2;
        int sk0 = (t & 3) * 32;
        int grow = r0 + srow;
#pragma unroll
        for (int j = 0; j < 4; ++j) {
            int k0 = sk0 + j * 8;
            short8 frag = {0, 0, 0, 0, 0, 0, 0, 0};
            if (grow < NN) frag = *(const short8*)(A + (size_t)grow * DD + k0);
            int byte = srow * 256 + k0 * 2;
            byte ^= (srow & 7) << 4;
            *(short8*)((char*)As + byte) = frag;
        }
    }
    __syncthreads();
    int w = t >> 6, l = t & 63;
    int c0 = w * 32;
    int lr = l & 15, lg = l >> 4;
    f32x4 acc[4][2] = {};
#pragma unroll
    for (int s = 0; s < 4; ++s) {
        short8 af[4];
#pragma unroll
        for (int f = 0; f < 4; ++f) {
            int rr = f * 16 + lr;
            int byte = rr * 256 + (s * 32 + lg * 8) * 2;
            byte ^= (rr & 7) << 4;
            af[f] = *(const short8*)((const char*)As + byte);
        }
#pragma unroll
        for (int g = 0; g < 2; ++g) {
            int col = c0 + g * 16 + lr;
            short8 bf = *(const short8*)&Wt[(size_t)col * DD + s * 32 + lg * 8];
#pragma unroll
            for (int f = 0; f < 4; ++f)
                acc[f][g] = __builtin_amdgcn_mfma_f32_16x16x32_bf16(af[f], bf, acc[f][g], 0, 0, 0);
        }
    }
    float sA[2] = {0.f, 0.f}, qA[2] = {0.f, 0.f};
#pragma unroll
    for (int g = 0; g < 2; ++g) {
        int col = c0 + g * 16 + lr;
        float b = bias[col];
#pragma unroll
        for (int f = 0; f < 4; ++f)
#pragma unroll
            for (int i = 0; i < 4; ++i) {
                int row = r0 + f * 16 + lg * 4 + i;
                if (row < NN) {
                    float o = fmaxf(acc[f][g][i] + b, 0.f);
                    C[(size_t)row * DD + col] = o;
                    sA[g] += o;
                    qA[g] += o * o;
                }
            }
    }
#pragma unroll
    for (int g = 0; g < 2; ++g) {
        sA[g] += __shfl_xor(sA[g], 16);
        sA[g] += __shfl_xor(sA[g], 32);
        qA[g] += __shfl_xor(qA[g], 16);
        qA[g] += __shfl_xor(qA[g], 32);
    }
    if (lg == 0)
#pragma unroll
        for (int g = 0; g < 2; ++g) {
            int col = c0 + g * 16 + lr;
            atomicAdd(&stats_out[col], sA[g]);
            atomicAdd(&stats_out[DD + col], qA[g]);
        }
}

// ---- batched GCN matmul: y = relu(A@W + rs*bias) -> bf16 to layout
// (Cbase + row*rowb + (col>>1)*pairb + (col&1)*2), stats of y. ----

struct MMB {
    const short* A[3];
    const short* W[3];
    const float* bias[3];
    const float* rs[3];
    float* stats[3];
    char* C[3];
    int rowb, pairb;
};

__global__ __launch_bounds__(256) void mfma_mm_gcn(MMB m) {
    int br = blockIdx.y;
    const short* A = m.A[br];
    const short* Wt = m.W[br];
    const float* bias = m.bias[br];
    const float* rs = m.rs[br];
    float* stats_out = m.stats[br];
    char* C = m.C[br];
    int rowb = m.rowb, pairb = m.pairb;

    __shared__ short As[64 * DD];
    int t = threadIdx.x;
    int r0 = blockIdx.x * 64;
    {
        int srow = t >> 2;
        int sk0 = (t & 3) * 32;
        int grow = r0 + srow;
#pragma unroll
        for (int j = 0; j < 4; ++j) {
            int k0 = sk0 + j * 8;
            short8 frag = {0, 0, 0, 0, 0, 0, 0, 0};
            if (grow < NN) frag = *(const short8*)(A + (size_t)grow * DD + k0);
            int byte = srow * 256 + k0 * 2;
            byte ^= (srow & 7) << 4;
            *(short8*)((char*)As + byte) = frag;
        }
    }
    __syncthreads();
    int w = t >> 6, l = t & 63;
    int c0 = w * 32;
    int lr = l & 15, lg = l >> 4;
    f32x4 acc[4][2] = {};
#pragma unroll
    for (int s = 0; s < 4; ++s) {
        short8 af[4];
#pragma unroll
        for (int f = 0; f < 4; ++f) {
            int rr = f * 16 + lr;
            int byte = rr * 256 + (s * 32 + lg * 8) * 2;
            byte ^= (rr & 7) << 4;
            af[f] = *(const short8*)((const char*)As + byte);
        }
#pragma unroll
        for (int g = 0; g < 2; ++g) {
            int col = c0 + g * 16 + lr;
            short8 bf = *(const short8*)&Wt[(size_t)col * DD + s * 32 + lg * 8];
#pragma unroll
            for (int f = 0; f < 4; ++f)
                acc[f][g] = __builtin_amdgcn_mfma_f32_16x16x32_bf16(af[f], bf, acc[f][g], 0, 0, 0);
        }
    }
    float rsv[4][4];
#pragma unroll
    for (int f = 0; f < 4; ++f)
#pragma unroll
        for (int i = 0; i < 4; ++i) {
            int row = r0 + f * 16 + lg * 4 + i;
            rsv[f][i] = (row < NN) ? rs[row] : 0.f;
        }
    float sA[2] = {0.f, 0.f}, qA[2] = {0.f, 0.f};
#pragma unroll
    for (int g = 0; g < 2; ++g) {
        int col = c0 + g * 16 + lr;
        float b = bias[col];
        size_t cb = (size_t)(col >> 1) * pairb + (col & 1) * 2;
#pragma unroll
        for (int f = 0; f < 4; ++f)
#pragma unroll
            for (int i = 0; i < 4; ++i) {
                int row = r0 + f * 16 + lg * 4 + i;
                if (row < NN) {
                    float o = fmaxf(acc[f][g][i] + rsv[f][i] * b, 0.f);
                    *(short*)(C + (size_t)row * rowb + cb) = (short)f2bf(o);
                    sA[g] += o;
                    qA[g] += o * o;
                }
            }
    }
#pragma unroll
    for (int g = 0; g < 2; ++g) {
        sA[g] += __shfl_xor(sA[g], 16);
        sA[g] += __shfl_xor(sA[g], 32);
        qA[g] += __shfl_xor(qA[g], 16);
        qA[g] += __shfl_xor(qA[g], 32);
    }
    if (lg == 0)
#pragma unroll
        for (int g = 0; g < 2; ++g) {
            int col = c0 + g * 16 + lr;
            atomicAdd(&stats_out[col], sA[g]);
            atomicAdd(&stats_out[DD + col], qA[g]);
        }
}

// ---- GAT pair matmul with fused attention; hn written to interleaved layout

template <int PRE>
__global__ __launch_bounds__(256) void mfma_mm_pair(const void* __restrict__ Av,
                                                    const short* __restrict__ Wt1,
                                                    const short* __restrict__ Wt2,
                                                    const float* __restrict__ b1,
                                                    const float* __restrict__ b2,
                                                    const float* __restrict__ a_se,
                                                    const float* __restrict__ a_ne,
                                                    const float* __restrict__ stats_in,
                                                    char* __restrict__ out2base, int rowb,
                                                    int pairb, float* __restrict__ ats_o,
                                                    float* __restrict__ atn_o) {
    __shared__ short As[64 * DD];
    __shared__ float mS[DD], sS[DD];
    int t = threadIdx.x;
    int r0 = blockIdx.x * 64;
    if (PRE == 1) {
        if (t < DD) {
            const float inv_n = 1.0f / (float)NN;
            float m = stats_in[t] * inv_n;
            float var = stats_in[DD + t] * inv_n - m * m;
            mS[t] = m;
            sS[t] = rsqrtf(var + 1e-9f);
        }
        __syncthreads();
    }
    {
        int srow = t >> 2;
        int sk0 = (t & 3) * 32;
        int grow = r0 + srow;
#pragma unroll
        for (int j = 0; j < 4; ++j) {
            int k0 = sk0 + j * 8;
            short8 frag = {0, 0, 0, 0, 0, 0, 0, 0};
            if (grow < NN) {
                if (PRE == 0) {
                    frag = *(const short8*)((const short*)Av + (size_t)grow * DD + k0);
                } else {
                    const float* Ar = (const float*)Av + (size_t)grow * DD;
                    float4 v0 = *(const float4*)(Ar + k0);
                    float4 v1 = *(const float4*)(Ar + k0 + 4);
                    float vv[8] = {v0.x, v0.y, v0.z, v0.w, v1.x, v1.y, v1.z, v1.w};
#pragma unroll
                    for (int e = 0; e < 8; ++e)
                        frag[e] = (short)f2bf((vv[e] - mS[k0 + e]) * sS[k0 + e]);
                }
            }
            int byte = srow * 256 + k0 * 2;
            byte ^= (srow & 7) << 4;
            *(short8*)((char*)As + byte) = frag;
        }
    }
    __syncthreads();
    int w = t >> 6, l = t & 63;
    int c0 = w * 32;
    int lr = l & 15, lg = l >> 4;
    f32x4 acc1[4][2] = {}, acc2[4][2] = {};
#pragma unroll
    for (int s = 0; s < 4; ++s) {
        short8 af[4];
#pragma unroll
        for (int f = 0; f < 4; ++f) {
            int rr = f * 16 + lr;
            int byte = rr * 256 + (s * 32 + lg * 8) * 2;
            byte ^= (rr & 7) << 4;
            af[f] = *(const short8*)((const char*)As + byte);
        }
#pragma unroll
        for (int g = 0; g < 2; ++g) {
            int col = c0 + g * 16 + lr;
            short8 bfa = *(const short8*)&Wt1[(size_t)col * DD + s * 32 + lg * 8];
            short8 bfb = *(const short8*)&Wt2[(size_t)col * DD + s * 32 + lg * 8];
#pragma unroll
            for (int f = 0; f < 4; ++f) {
                acc1[f][g] = __builtin_amdgcn_mfma_f32_16x16x32_bf16(af[f], bfa, acc1[f][g], 0, 0, 0);
                acc2[f][g] = __builtin_amdgcn_mfma_f32_16x16x32_bf16(af[f], bfb, acc2[f][g], 0, 0, 0);
            }
        }
    }
#pragma unroll
    for (int g = 0; g < 2; ++g) {
        int colc = c0 + g * 16 + lr;
        float bb1 = b1[colc], bb2 = b2[colc];
        float asv = a_se[colc], anv = a_ne[colc];
        int h = (c0 >> 4) + g;
        size_t cb = (size_t)(colc >> 1) * pairb + (colc & 1) * 2;
#pragma unroll
        for (int f = 0; f < 4; ++f)
#pragma unroll
            for (int i = 0; i < 4; ++i) {
                int row = r0 + f * 16 + lg * 4 + i;
                float o1 = fmaxf(acc1[f][g][i] + bb1, 0.f);  // hs (ephemeral)
                float o2 = fmaxf(acc2[f][g][i] + bb2, 0.f);  // hn
                if (row < NN) *(short*)(out2base + (size_t)row * rowb + cb) = (short)f2bf(o2);
                float ds = o1 * asv, dn = o1 * anv;
                ds += __shfl_xor(ds, 1);
                dn += __shfl_xor(dn, 1);
                ds += __shfl_xor(ds, 2);
                dn += __shfl_xor(dn, 2);
                ds += __shfl_xor(ds, 4);
                dn += __shfl_xor(dn, 4);
                ds += __shfl_xor(ds, 8);
                dn += __shfl_xor(dn, 8);
                if (lr == 0 && row < NN) {
                    ats_o[row * NH + h] = ds > 0.f ? ds : 0.2f * ds;
                    atn_o[row * NH + h] = dn > 0.f ? dn : 0.2f * dn;
                }
            }
    }
}

// ---------------- fused gather pass A: GAT-L0 + 3x GCN-L0 (G2 dwordx2) ------
// NOTE: grid covers exactly NN rows (NN % 4 == 0) -> no early return, barriers safe.

__global__ __launch_bounds__(256) void spmm_fusedA(
    const char* __restrict__ G2, const float* __restrict__ ats, const float* __restrict__ atn,
    const int4* __restrict__ ed, const int* __restrict__ row_ptr, float* __restrict__ aggG,
    short* __restrict__ zu, short* __restrict__ zp, short* __restrict__ zf,
    float* __restrict__ rs_all, float* __restrict__ stats0) {
    __shared__ float sred[2 * DD];
    int t = threadIdx.x;
    sred[t] = 0.f;
    __syncthreads();
    int r = __builtin_amdgcn_readfirstlane((blockIdx.x * 256 + t) >> 6);
    int lane = t & 63;
    int hh = lane >> 3;
    float a_s = ats[r * NH + hh];
    int start = row_ptr[r], end = row_ptr[r + 1];
    float2 ag = {0.f, 0.f}, au = {0.f, 0.f}, ap = {0.f, 0.f}, af2 = {0.f, 0.f};
    float su = 0.f, sp = 0.f, sf = 0.f;
    int j = start;
    for (; j + 2 <= end; j += 2) {
        int4 a0 = ed[2 * j], b0 = ed[2 * j + 1];
        int4 a1 = ed[2 * j + 2], b1 = ed[2 * j + 3];
        int cA = a0.x, cB = a1.x;
        float at0 = atn[cA * NH + hh], at1 = atn[cB * NH + hh];
        uint2 d0 = *(const uint2*)(G2 + (size_t)cA * 512 + lane * 8);
        uint2 d1 = *(const uint2*)(G2 + (size_t)cB * 512 + lane * 8);
        {
            float vg = __int_as_float(a0.y), vu = __int_as_float(a0.z);
            float vp = __int_as_float(a0.w), vf = __int_as_float(b0.x);
            float e = (a_s + at0) * vg;
            float flo = bflo(d0.x), fhi = bfhi(d0.x), glo = bflo(d0.y), ghi = bfhi(d0.y);
            ag.x += e * glo;  ag.y += e * ghi;
            au.x += vu * flo; au.y += vu * fhi;
            ap.x += vp * flo; ap.y += vp * fhi;
            af2.x += vf * flo; af2.y += vf * fhi;
            su += vu; sp += vp; sf += vf;
        }
        {
            float vg = __int_as_float(a1.y), vu = __int_as_float(a1.z);
            float vp = __int_as_float(a1.w), vf = __int_as_float(b1.x);
            float e = (a_s + at1) * vg;
            float flo = bflo(d1.x), fhi = bfhi(d1.x), glo = bflo(d1.y), ghi = bfhi(d1.y);
            ag.x += e * glo;  ag.y += e * ghi;
            au.x += vu * flo; au.y += vu * fhi;
            ap.x += vp * flo; ap.y += vp * fhi;
            af2.x += vf * flo; af2.y += vf * fhi;
            su += vu; sp += vp; sf += vf;
        }
    }
    if (j < end) {
        int4 a0 = ed[2 * j], b0 = ed[2 * j + 1];
        int cA = a0.x;
        float at0 = atn[cA * NH + hh];
        uint2 d0 = *(const uint2*)(G2 + (size_t)cA * 512 + lane * 8);
        float vg = __int_as_float(a0.y), vu = __int_as_float(a0.z);
        float vp = __int_as_float(a0.w), vf = __int_as_float(b0.x);
        float e = (a_s + at0) * vg;
        float flo = bflo(d0.x), fhi = bfhi(d0.x), glo = bflo(d0.y), ghi = bfhi(d0.y);
        ag.x += e * glo;  ag.y += e * ghi;
        au.x += vu * flo; au.y += vu * fhi;
        ap.x += vp * flo; ap.y += vp * fhi;
        af2.x += vf * flo; af2.y += vf * fhi;
        su += vu; sp += vp; sf += vf;
    }
    size_t o = (size_t)r * DD + lane * 2;
    *(float2*)&aggG[o] = ag;
    *(unsigned int*)(zu + o) = pack2bf(au.x, au.y);
    *(unsigned int*)(zp + o) = pack2bf(ap.x, ap.y);
    *(unsigned int*)(zf + o) = pack2bf(af2.x, af2.y);
    if (lane == 0) {
        rs_all[r] = su;
        rs_all[NN + r] = sp;
        rs_all[2 * NN + r] = sf;
    }
    // fused BN stats of GAT L0 agg (lane holds cols 2*lane, 2*lane+1)
    atomicAdd(&sred[2 * lane], ag.x);
    atomicAdd(&sred[2 * lane + 1], ag.y);
    atomicAdd(&sred[DD + 2 * lane], ag.x * ag.x);
    atomicAdd(&sred[DD + 2 * lane + 1], ag.y * ag.y);
    __syncthreads();
    atomicAdd(&stats0[t], sred[t]);
}

// ---------------- fused gather pass B: GAT-L1 + 3x GCN-L1 (G4 dwordx4) ------

__global__ __launch_bounds__(256) void spmm_fusedB(
    const char* __restrict__ G4, const float* __restrict__ ats, const float* __restrict__ atn,
    const int4* __restrict__ ed, const int* __restrict__ row_ptr, float* __restrict__ aggG,
    short* __restrict__ z1u, short* __restrict__ z1p, short* __restrict__ z1f,
    float* __restrict__ stats1) {
    __shared__ float sred[2 * DD];
    int t = threadIdx.x;
    sred[t] = 0.f;
    __syncthreads();
    int r = __builtin_amdgcn_readfirstlane((blockIdx.x * 256 + t) >> 6);
    int lane = t & 63;
    int hh = lane >> 3;
    float a_s = ats[r * NH + hh];
    int start = row_ptr[r], end = row_ptr[r + 1];
    float2 ag = {0.f, 0.f}, au = {0.f, 0.f}, ap = {0.f, 0.f}, af2 = {0.f, 0.f};
    int j = start;
    for (; j + 2 <= end; j += 2) {
        int4 a0 = ed[2 * j], b0 = ed[2 * j + 1];
        int4 a1 = ed[2 * j + 2], b1 = ed[2 * j + 3];
        int cA = a0.x, cB = a1.x;
        float at0 = atn[cA * NH + hh], at1 = atn[cB * NH + hh];
        uint4 d0 = *(const uint4*)(G4 + (size_t)cA * 1024 + lane * 16);
        uint4 d1 = *(const uint4*)(G4 + (size_t)cB * 1024 + lane * 16);
        float e0 = (a_s + at0) * __int_as_float(a0.y);
        float e1 = (a_s + at1) * __int_as_float(a1.y);
        float vu0 = __int_as_float(a0.z), vp0 = __int_as_float(a0.w), vf0 = __int_as_float(b0.x);
        float vu1 = __int_as_float(a1.z), vp1 = __int_as_float(a1.w), vf1 = __int_as_float(b1.x);
        ag.x += e0 * bflo(d0.x) + e1 * bflo(d1.x);
        ag.y += e0 * bfhi(d0.x) + e1 * bfhi(d1.x);
        au.x += vu0 * bflo(d0.y) + vu1 * bflo(d1.y);
        au.y += vu0 * bfhi(d0.y) + vu1 * bfhi(d1.y);
        ap.x += vp0 * bflo(d0.z) + vp1 * bflo(d1.z);
        ap.y += vp0 * bfhi(d0.z) + vp1 * bfhi(d1.z);
        af2.x += vf0 * bflo(d0.w) + vf1 * bflo(d1.w);
        af2.y += vf0 * bfhi(d0.w) + vf1 * bfhi(d1.w);
    }
    if (j < end) {
        int4 a0 = ed[2 * j], b0 = ed[2 * j + 1];
        int cA = a0.x;
        float at0 = atn[cA * NH + hh];
        uint4 d0 = *(const uint4*)(G4 + (size_t)cA * 1024 + lane * 16);
        float e0 = (a_s + at0) * __int_as_float(a0.y);
        float vu0 = __int_as_float(a0.z), vp0 = __int_as_float(a0.w), vf0 = __int_as_float(b0.x);
        ag.x += e0 * bflo(d0.x);
        ag.y += e0 * bfhi(d0.x);
        au.x += vu0 * bflo(d0.y);
        au.y += vu0 * bfhi(d0.y);
        ap.x += vp0 * bflo(d0.z);
        ap.y += vp0 * bfhi(d0.z);
        af2.x += vf0 * bflo(d0.w);
        af2.y += vf0 * bfhi(d0.w);
    }
    size_t o = (size_t)r * DD + lane * 2;
    *(float2*)&aggG[o] = ag;
    *(unsigned int*)(z1u + o) = pack2bf(au.x, au.y);
    *(unsigned int*)(z1p + o) = pack2bf(ap.x, ap.y);
    *(unsigned int*)(z1f + o) = pack2bf(af2.x, af2.y);
    atomicAdd(&sred[2 * lane], ag.x);
    atomicAdd(&sred[2 * lane + 1], ag.y);
    atomicAdd(&sred[DD + 2 * lane], ag.x * ag.x);
    atomicAdd(&sred[DD + 2 * lane + 1], ag.y * ag.y);
    __syncthreads();
    atomicAdd(&stats1[t], sred[t]);
}

// ---------------- classifier (fp32 input; GAT/self) ----------------

template <bool FIRST>
__global__ __launch_bounds__(256) void cls_acc_kernel(const float* __restrict__ o,
                                                      const float* __restrict__ Wc,
                                                      const float* __restrict__ stats,
                                                      const float* __restrict__ b_cls,
                                                      float* __restrict__ out) {
    __shared__ float Wl[DD * NCLS];
    __shared__ float mS[DD], sS[DD];
    int t = threadIdx.x;
    for (int i = t; i < DD * NCLS; i += 256) Wl[i] = Wc[i];
    if (t < DD) {
        const float inv_n = 1.0f / (float)NN;
        float m = stats[t] * inv_n;
        float var = stats[DD + t] * inv_n - m * m;
        mS[t] = m;
        sS[t] = rsqrtf(var + 1e-9f);
    }
    __syncthreads();
    int n = blockIdx.x * 256 + t;
    if (n >= NN) return;
    float acc[NCLS] = {};
    const float4* orow = (const float4*)(o + (size_t)n * DD);
    for (int k4 = 0; k4 < DD / 4; ++k4) {
        float4 v = orow[k4];
#pragma unroll
        for (int kk = 0; kk < 4; ++kk) {
            int k = k4 * 4 + kk;
            float a = (((const float*)&v)[kk] - mS[k]) * sS[k];
#pragma unroll
            for (int c = 0; c < NCLS; ++c) acc[c] += a * Wl[k * NCLS + c];
        }
    }
#pragma unroll
    for (int c = 0; c < NCLS; ++c) {
        if (FIRST)
            out[n * NCLS + c] = acc[c] + b_cls[c];
        else
            out[n * NCLS + c] += acc[c];
    }
}

// ---- batched GCN classifier (bf16 y1, BN via stats; atomic accumulate) ----

struct CLS3 {
    const short* o[3];
    const float* stats[3];
};

__global__ __launch_bounds__(256) void cls3_kernel(CLS3 a, const float* __restrict__ W_cls,
                                                   float* __restrict__ out) {
    int br = blockIdx.y;
    const short* o = a.o[br];
    const float* st = a.stats[br];
    const float* Wc = W_cls + (size_t)(DD + DD * br) * NCLS;
    __shared__ float Wl[DD * NCLS];
    __shared__ float mS[DD], sS[DD];
    int t = threadIdx.x;
    for (int i = t; i < DD * NCLS; i += 256) Wl[i] = Wc[i];
    if (t < DD) {
        const float inv_n = 1.0f / (float)NN;
        float m = st[t] * inv_n;
        float var = st[DD + t] * inv_n - m * m;
        mS[t] = m;
        sS[t] = rsqrtf(var + 1e-9f);
    }
    __syncthreads();
    int n = blockIdx.x * 256 + t;
    if (n >= NN) return;
    float acc[NCLS] = {};
    const uint4* orow = (const uint4*)(o + (size_t)n * DD);
    for (int k8 = 0; k8 < DD / 8; ++k8) {
        uint4 v = orow[k8];
        float vv[8] = {bflo(v.x), bfhi(v.x), bflo(v.y), bfhi(v.y),
                       bflo(v.z), bfhi(v.z), bflo(v.w), bfhi(v.w)};
#pragma unroll
        for (int kk = 0; kk < 8; ++kk) {
            int k = k8 * 8 + kk;
            float a2 = (vv[kk] - mS[k]) * sS[k];
#pragma unroll
            for (int c = 0; c < NCLS; ++c) acc[c] += a2 * Wl[k * NCLS + c];
        }
    }
#pragma unroll
    for (int c = 0; c < NCLS; ++c) atomicAdd(&out[n * NCLS + c], acc[c]);
}

// ---------------------------------------------------------------------------

extern "C" void kernel_launch(void* const* d_in, const int* in_sizes, int n_in, void* d_out,
                              int out_size, void* d_ws, size_t ws_size, hipStream_t stream) {
    const float* f_in = (const float*)d_in[0];
    const int* edge_row = (const int*)d_in[1];
    const int* edge_col = (const int*)d_in[2];
    const float* vals_gat = (const float*)d_in[3];
    const float* vals_uttr = (const float*)d_in[4];
    const float* vals_past = (const float*)d_in[5];
    const float* vals_futr = (const float*)d_in[6];
    const float* gat_Ws = (const float*)d_in[7];
    const float* gat_bs = (const float*)d_in[8];
    const float* gat_Wn = (const float*)d_in[9];
    const float* gat_bn = (const float*)d_in[10];
    const float* gat_as = (const float*)d_in[11];
    const float* gat_an = (const float*)d_in[12];
    const float* W_uttr = (const float*)d_in[13];
    const float* b_uttr = (const float*)d_in[14];
    const float* W_past = (const float*)d_in[15];
    const float* b_past = (const float*)d_in[16];
    const float* W_futr = (const float*)d_in[17];
    const float* b_futr = (const float*)d_in[18];
    const float* W_self = (const float*)d_in[19];
    const float* b_self = (const float*)d_in[20];
    const float* W_cls = (const float*)d_in[21];
    const float* b_cls = (const float*)d_in[22];
    float* out = (float*)d_out;

    char* ws = (char*)d_ws;
    size_t off = 0;
    auto alloc = [&](size_t bytes) -> void* {
        void* p = ws + off;
        off = (off + bytes + 255) & ~(size_t)255;
        return p;
    };
    float* stats_all = (float*)alloc(9 * 2 * DD * 4);
    int* cnt = (int*)alloc((size_t)NN * 4);  // adjacent to stats -> one memset
    float* tmp1 = (float*)alloc((size_t)NN * DD * 4);  // self h; later z1p/z1f
    float* bufA = (float*)alloc((size_t)NN * DD * 4);  // GAT agg L0/L1
    short* fbf = (short*)alloc((size_t)NN * DD * 2);   // f_in bf16; later z1u
    char* G2 = (char*)alloc((size_t)NN * 512);         // [node][lane][fbf,hnL0]
    char* G4 = (char*)alloc((size_t)NN * 1024);        // [node][lane][hnL1,y0u,y0p,y0f]
    short* z0u = (short*)alloc((size_t)NN * DD * 2);   // z0; later y1
    short* z0p = (short*)alloc((size_t)NN * DD * 2);
    short* z0f = (short*)alloc((size_t)NN * DD * 2);
    float* rs_all = (float*)alloc((size_t)3 * NN * 4);
    float* ats_b = (float*)alloc((size_t)NN * NH * 4);
    float* atn_b = (float*)alloc((size_t)NN * NH * 4);
    short* Wt_all = (short*)alloc((size_t)14 * DD * DD * 2);
    float* bfix = (float*)alloc((size_t)3 * DD * 4);
    int* row_ptr = (int*)alloc((size_t)(NN + 1) * 4);
    int* fill = (int*)alloc((size_t)NN * 4);
    int* pre_b = (int*)alloc((size_t)NN * 4);
    int* bsum = (int*)alloc((size_t)SCAN_B * 4);
    int* boff = (int*)alloc((size_t)257 * 4);
    int4* ed = (int4*)alloc((size_t)NE * 32);

    auto stats = [&](int s) { return stats_all + (size_t)s * 2 * DD; };
    auto Wt = [&](int w) { return Wt_all + (size_t)w * DD * DD; };
    // stats: 0=GAT L0 agg, 1=GAT L1 agg, 2..4=GCN y0, 5..7=GCN y1, 8=self

    const int gE = (NE + 255) / 256;
    const int gMM = (NN + 63) / 64;
    const int gSP = NN / 4;  // exact (NN % 4 == 0)
    const int gCA = (NN + 255) / 256;
    const int gBF = (NN * DD / 8 + 255) / 256;

    hipMemsetAsync(stats_all, 0, 9 * 2 * DD * 4 + (size_t)NN * 4, stream);

    // CSR build
    count_kernel<<<gE, 256, 0, stream>>>(edge_row, cnt);
    scan1_kernel<<<SCAN_B, 256, 0, stream>>>(cnt, pre_b, bsum);
    scan2_kernel<<<1, 256, 0, stream>>>(bsum, boff);
    scan3_kernel<<<SCAN_B, 256, 0, stream>>>(pre_b, boff, row_ptr, fill);
    scatter_kernel<<<gE, 256, 0, stream>>>(edge_row, edge_col, vals_gat, vals_uttr, vals_past,
                                           vals_futr, fill, ed);

    tobf16_kernel<<<gBF, 256, 0, stream>>>(f_in, fbf, G2);

    WPrepArgs wa;
    wa.src[0] = gat_Ws;
    wa.src[1] = gat_Wn;
    wa.src[2] = gat_Ws + (size_t)DD * DD;
    wa.src[3] = gat_Wn + (size_t)DD * DD;
    wa.src[4] = W_uttr;
    wa.src[5] = W_uttr + (size_t)DD * DD;  // unused slot
    wa.src[6] = W_past;
    wa.src[7] = W_past + (size_t)DD * DD;  // unused slot
    wa.src[8] = W_futr;
    wa.src[9] = W_futr + (size_t)DD * DD;  // unused slot
    wa.src[10] = W_self;
    wprep_kernel<<<(11 * DD * DD + 255) / 256, 256, 0, stream>>>(wa, Wt_all);

    // ---- self branch (FIRST classifier write) ----
    mfma_mm_self<<<gMM, 256, 0, stream>>>(fbf, Wt(10), b_self, stats(8), tmp1);
    cls_acc_kernel<true><<<gCA, 256, 0, stream>>>(tmp1, W_cls + (size_t)4 * DD * NCLS, stats(8),
                                                  b_cls, out);

    // ---- GAT L0 (hn -> G2 slice 1) + fused gather A ----
    mfma_mm_pair<0><<<gMM, 256, 0, stream>>>(fbf, Wt(0), Wt(1), gat_bs, gat_bn, gat_as, gat_an,
                                             nullptr, G2 + 4, 512, 8, ats_b, atn_b);
    spmm_fusedA<<<gSP, 256, 0, stream>>>(G2, ats_b, atn_b, ed, row_ptr, bufA, z0u, z0p, z0f,
                                         rs_all, stats(0));

    // ---- GAT L1 matmul (BN on the fly; hn -> G4 slice 0) ----
    mfma_mm_pair<1><<<gMM, 256, 0, stream>>>(bufA, Wt(2), Wt(3), gat_bs + DD, gat_bn + DD,
                                             gat_as + DD, gat_an + DD, stats(0), G4, 1024, 16,
                                             ats_b, atn_b);

    // ---- GCN L0 matmuls (batched, z0 -> y0 into G4 slices 1..3) ----
    const float* bb[3] = {b_uttr, b_past, b_futr};
    const float* Worig[3] = {W_uttr, W_past, W_futr};
    short* z0a[3] = {z0u, z0p, z0f};
    MMB m0;
    for (int br = 0; br < 3; ++br) {
        m0.A[br] = z0a[br];
        m0.W[br] = Wt(4 + br * 2);
        m0.bias[br] = bb[br];
        m0.rs[br] = rs_all + (size_t)br * NN;
        m0.stats[br] = stats(2 + br);
        m0.C[br] = G4 + 4 + br * 4;
    }
    m0.rowb = 1024;
    m0.pairb = 16;
    mfma_mm_gcn<<<dim3(gMM, 3), 256, 0, stream>>>(m0);

    // ---- wfix: fold BN(y0) into L1 weights ----
    WFixArgs wf;
    for (int br = 0; br < 3; ++br) {
        wf.W1[br] = Worig[br] + (size_t)DD * DD;
        wf.b1[br] = bb[br] + DD;
        wf.stats[br] = stats(2 + br);
    }
    wfix_kernel<<<2, 256, 0, stream>>>(wf, Wt(11), bfix);

    // ---- fused gather B: GAT-L1 agg + 3x GCN z1 ----
    short* z1u = fbf;           // fbf dead
    short* z1p = (short*)tmp1;  // tmp1 dead after self cls
    short* z1f = (short*)tmp1 + (size_t)NN * DD;
    spmm_fusedB<<<gSP, 256, 0, stream>>>(G4, ats_b, atn_b, ed, row_ptr, bufA, z1u, z1p, z1f,
                                         stats(1));
    cls_acc_kernel<false><<<gCA, 256, 0, stream>>>(bufA, W_cls, stats(1), b_cls, out);

    // ---- GCN L1 matmuls (batched, z1 -> y1 plain bf16 in z0 slots) ----
    MMB m1;
    short* z1a[3] = {z1u, z1p, z1f};
    for (int br = 0; br < 3; ++br) {
        m1.A[br] = z1a[br];
        m1.W[br] = Wt(11 + br);
        m1.bias[br] = bfix + (size_t)br * DD;
        m1.rs[br] = rs_all + (size_t)br * NN;
        m1.stats[br] = stats(5 + br);
        m1.C[br] = (char*)z0a[br];
    }
    m1.rowb = 256;
    m1.pairb = 4;
    mfma_mm_gcn<<<dim3(gMM, 3), 256, 0, stream>>>(m1);

    // ---- batched GCN classifiers ----
    CLS3 c3;
    for (int br = 0; br < 3; ++br) {
        c3.o[br] = z0a[br];
        c3.stats[br] = stats(5 + br);
    }
    cls3_kernel<<<dim3(gCA, 3), 256, 0, stream>>>(c3, W_cls, out);
}

// Round 9
// 598.664 us; speedup vs baseline: 1.7429x; 1.7429x over previous
//
#include <hip/hip_runtime.h>
#include <hip/hip_bf16.h>

// ---------------------------------------------------------------------------
// ERCGNN R8 (resubmit after infra failure): R6's interleaved gather layouts
// (G2/G4) KEPT; fused BN-stats atomics REVERTED to standalone 256-block
// bn_stats (R7 regression: 3.2M contended global atomics onto 1KB region).
// ---------------------------------------------------------------------------

#define NN 50000
#define NE 500000
#define DD 128
#define NH 8
#define DHD 16
#define NCLS 7
#define SCAN_B 196  // ceil(50000/256)

typedef __attribute__((ext_vector_type(8))) short short8;
typedef __attribute__((ext_vector_type(4))) float f32x4;

__device__ __forceinline__ unsigned short f2bf(float x) {
    unsigned int u = __float_as_uint(x);
    unsigned int r = (u + 0x7fffu + ((u >> 16) & 1u)) >> 16;  // RNE
    return (unsigned short)r;
}
__device__ __forceinline__ unsigned int pack2bf(float lo, float hi) {
    return (unsigned int)f2bf(lo) | ((unsigned int)f2bf(hi) << 16);
}
__device__ __forceinline__ float bflo(unsigned int u) { return __uint_as_float(u << 16); }
__device__ __forceinline__ float bfhi(unsigned int u) { return __uint_as_float(u & 0xffff0000u); }

// ---------------- CSR build ----------------

__global__ void count_kernel(const int* __restrict__ row, int* __restrict__ cnt) {
    int e = blockIdx.x * 256 + threadIdx.x;
    if (e < NE) atomicAdd(&cnt[row[e]], 1);
}

__global__ __launch_bounds__(256) void scan1_kernel(const int* __restrict__ cnt,
                                                    int* __restrict__ pre,
                                                    int* __restrict__ bsum) {
    __shared__ int s[256];
    int t = threadIdx.x;
    int i = blockIdx.x * 256 + t;
    int v = (i < NN) ? cnt[i] : 0;
    s[t] = v;
    __syncthreads();
    for (int off = 1; off < 256; off <<= 1) {
        int u = (t >= off) ? s[t - off] : 0;
        __syncthreads();
        s[t] += u;
        __syncthreads();
    }
    if (i < NN) pre[i] = s[t] - v;
    if (t == 255) bsum[blockIdx.x] = s[255];
}

__global__ __launch_bounds__(256) void scan2_kernel(const int* __restrict__ bsum,
                                                    int* __restrict__ boff) {
    __shared__ int s[256];
    int t = threadIdx.x;
    int v = (t < SCAN_B) ? bsum[t] : 0;
    s[t] = v;
    __syncthreads();
    for (int off = 1; off < 256; off <<= 1) {
        int u = (t >= off) ? s[t - off] : 0;
        __syncthreads();
        s[t] += u;
        __syncthreads();
    }
    boff[t] = s[t] - v;
    if (t == 255) boff[256] = s[255];
}

__global__ __launch_bounds__(256) void scan3_kernel(const int* __restrict__ pre,
                                                    const int* __restrict__ boff,
                                                    int* __restrict__ row_ptr,
                                                    int* __restrict__ fill) {
    int t = threadIdx.x;
    int i = blockIdx.x * 256 + t;
    if (i < NN) {
        int v = pre[i] + boff[blockIdx.x];
        row_ptr[i] = v;
        fill[i] = v;
    }
    if (blockIdx.x == 0 && t == 0) row_ptr[NN] = boff[256];
}

// 32B edge record: {col, vg, vu, vp} {vf, 0, 0, 0}
__global__ void scatter_kernel(const int* __restrict__ row, const int* __restrict__ col,
                               const float* __restrict__ vg, const float* __restrict__ vu,
                               const float* __restrict__ vp, const float* __restrict__ vf,
                               int* __restrict__ fill, int4* __restrict__ ed) {
    int e = blockIdx.x * 256 + threadIdx.x;
    if (e >= NE) return;
    int r = row[e];
    int pos = atomicAdd(&fill[r], 1);
    ed[2 * pos] = make_int4(col[e], __float_as_int(vg[e]), __float_as_int(vu[e]),
                            __float_as_int(vp[e]));
    ed[2 * pos + 1] = make_int4(__float_as_int(vf[e]), 0, 0, 0);
}

// ---------------- fp32 -> bf16 (plain fbf + G2 slice 0) ----------------

__global__ __launch_bounds__(256) void tobf16_kernel(const float* __restrict__ x,
                                                     short* __restrict__ y,
                                                     char* __restrict__ G2) {
    int idx = blockIdx.x * 256 + threadIdx.x;  // 8 feats each
    if (idx >= NN * DD / 8) return;
    int node = idx >> 4;
    int k0 = (idx & 15) * 8;
    float4 a = ((const float4*)x)[idx * 2];
    float4 b = ((const float4*)x)[idx * 2 + 1];
    uint4 o;
    o.x = pack2bf(a.x, a.y);
    o.y = pack2bf(a.z, a.w);
    o.z = pack2bf(b.x, b.y);
    o.w = pack2bf(b.z, b.w);
    *(uint4*)(y + (size_t)idx * 8) = o;
    char* g = G2 + (size_t)node * 512 + (k0 >> 1) * 8;
    *(unsigned int*)(g) = o.x;
    *(unsigned int*)(g + 8) = o.y;
    *(unsigned int*)(g + 16) = o.z;
    *(unsigned int*)(g + 24) = o.w;
}

// ---------------- weight prep ----------------

struct WPrepArgs {
    const float* src[11];
};

__global__ __launch_bounds__(256) void wprep_kernel(WPrepArgs a, short* __restrict__ out) {
    int idx = blockIdx.x * 256 + threadIdx.x;
    if (idx >= 11 * DD * DD) return;
    int w = idx >> 14;
    int r = idx & 16383;
    int n = r >> 7, k = r & 127;
    const float* W = a.src[w];
    float v = (w < 4) ? W[(size_t)((n >> 4) * DD + k) * DHD + (n & 15)] : W[(size_t)k * DD + n];
    out[idx] = (short)f2bf(v);
}

// ---- wfix: fold BN(y0) into L1 weights ----

struct WFixArgs {
    const float* W1[3];
    const float* b1[3];
    const float* stats[3];
};

__global__ __launch_bounds__(256) void wfix_kernel(WFixArgs a, short* __restrict__ wt_out,
                                                   float* __restrict__ bfix) {
    int idx = blockIdx.x * 256 + threadIdx.x;
    if (idx >= 3 * DD) return;
    int br = idx >> 7, n = idx & 127;
    const float* st = a.stats[br];
    const float* W = a.W1[br];
    const float inv_n = 1.0f / (float)NN;
    float accb = 0.f;
    short* wo = wt_out + (size_t)br * DD * DD + (size_t)n * DD;
#pragma unroll 4
    for (int k = 0; k < DD; ++k) {
        float m = st[k] * inv_n;
        float var = st[DD + k] * inv_n - m * m;
        float s = rsqrtf(var + 1e-9f);
        float w = W[(size_t)k * DD + n];
        wo[k] = (short)f2bf(s * w);
        accb += m * s * w;
    }
    bfix[idx] = a.b1[br][n] - accb;
}

// ---------------- BN stats (256 blocks, low-contention atomics) -------------

__global__ __launch_bounds__(256) void bn_stats_kernel(const float* __restrict__ x,
                                                       float* __restrict__ stats) {
    int c = threadIdx.x & 127;
    int sub = threadIdx.x >> 7;
    int rows_per_block = (NN + gridDim.x - 1) / gridDim.x;
    int rbeg = blockIdx.x * rows_per_block;
    int rend = min(rbeg + rows_per_block, NN);
    float s = 0.f, q = 0.f;
    for (int r = rbeg + sub; r < rend; r += 2) {
        float v = x[(size_t)r * DD + c];
        s += v;
        q += v * v;
    }
    atomicAdd(&stats[c], s);
    atomicAdd(&stats[DD + c], q);
}

// ---------------- self matmul: bf16 A -> fp32 relu C, stats ----------------

__global__ __launch_bounds__(256) void mfma_mm_self(const short* __restrict__ A,
                                                    const short* __restrict__ Wt,
                                                    const float* __restrict__ bias,
                                                    float* __restrict__ stats_out,
                                                    float* __restrict__ C) {
    __shared__ short As[64 * DD];
    int t = threadIdx.x;
    int r0 = blockIdx.x * 64;
    {
        int srow = t >> 2;
        int sk0 = (t & 3) * 32;
        int grow = r0 + srow;
#pragma unroll
        for (int j = 0; j < 4; ++j) {
            int k0 = sk0 + j * 8;
            short8 frag = {0, 0, 0, 0, 0, 0, 0, 0};
            if (grow < NN) frag = *(const short8*)(A + (size_t)grow * DD + k0);
            int byte = srow * 256 + k0 * 2;
            byte ^= (srow & 7) << 4;
            *(short8*)((char*)As + byte) = frag;
        }
    }
    __syncthreads();
    int w = t >> 6, l = t & 63;
    int c0 = w * 32;
    int lr = l & 15, lg = l >> 4;
    f32x4 acc[4][2] = {};
#pragma unroll
    for (int s = 0; s < 4; ++s) {
        short8 af[4];
#pragma unroll
        for (int f = 0; f < 4; ++f) {
            int rr = f * 16 + lr;
            int byte = rr * 256 + (s * 32 + lg * 8) * 2;
            byte ^= (rr & 7) << 4;
            af[f] = *(const short8*)((const char*)As + byte);
        }
#pragma unroll
        for (int g = 0; g < 2; ++g) {
            int col = c0 + g * 16 + lr;
            short8 bf = *(const short8*)&Wt[(size_t)col * DD + s * 32 + lg * 8];
#pragma unroll
            for (int f = 0; f < 4; ++f)
                acc[f][g] = __builtin_amdgcn_mfma_f32_16x16x32_bf16(af[f], bf, acc[f][g], 0, 0, 0);
        }
    }
    float sA[2] = {0.f, 0.f}, qA[2] = {0.f, 0.f};
#pragma unroll
    for (int g = 0; g < 2; ++g) {
        int col = c0 + g * 16 + lr;
        float b = bias[col];
#pragma unroll
        for (int f = 0; f < 4; ++f)
#pragma unroll
            for (int i = 0; i < 4; ++i) {
                int row = r0 + f * 16 + lg * 4 + i;
                if (row < NN) {
                    float o = fmaxf(acc[f][g][i] + b, 0.f);
                    C[(size_t)row * DD + col] = o;
                    sA[g] += o;
                    qA[g] += o * o;
                }
            }
    }
#pragma unroll
    for (int g = 0; g < 2; ++g) {
        sA[g] += __shfl_xor(sA[g], 16);
        sA[g] += __shfl_xor(sA[g], 32);
        qA[g] += __shfl_xor(qA[g], 16);
        qA[g] += __shfl_xor(qA[g], 32);
    }
    if (lg == 0)
#pragma unroll
        for (int g = 0; g < 2; ++g) {
            int col = c0 + g * 16 + lr;
            atomicAdd(&stats_out[col], sA[g]);
            atomicAdd(&stats_out[DD + col], qA[g]);
        }
}

// ---- batched GCN matmul: y = relu(A@W + rs*bias) -> bf16 to layout
// (Cbase + row*rowb + (col>>1)*pairb + (col&1)*2), stats of y. ----

struct MMB {
    const short* A[3];
    const short* W[3];
    const float* bias[3];
    const float* rs[3];
    float* stats[3];
    char* C[3];
    int rowb, pairb;
};

__global__ __launch_bounds__(256) void mfma_mm_gcn(MMB m) {
    int br = blockIdx.y;
    const short* A = m.A[br];
    const short* Wt = m.W[br];
    const float* bias = m.bias[br];
    const float* rs = m.rs[br];
    float* stats_out = m.stats[br];
    char* C = m.C[br];
    int rowb = m.rowb, pairb = m.pairb;

    __shared__ short As[64 * DD];
    int t = threadIdx.x;
    int r0 = blockIdx.x * 64;
    {
        int srow = t >> 2;
        int sk0 = (t & 3) * 32;
        int grow = r0 + srow;
#pragma unroll
        for (int j = 0; j < 4; ++j) {
            int k0 = sk0 + j * 8;
            short8 frag = {0, 0, 0, 0, 0, 0, 0, 0};
            if (grow < NN) frag = *(const short8*)(A + (size_t)grow * DD + k0);
            int byte = srow * 256 + k0 * 2;
            byte ^= (srow & 7) << 4;
            *(short8*)((char*)As + byte) = frag;
        }
    }
    __syncthreads();
    int w = t >> 6, l = t & 63;
    int c0 = w * 32;
    int lr = l & 15, lg = l >> 4;
    f32x4 acc[4][2] = {};
#pragma unroll
    for (int s = 0; s < 4; ++s) {
        short8 af[4];
#pragma unroll
        for (int f = 0; f < 4; ++f) {
            int rr = f * 16 + lr;
            int byte = rr * 256 + (s * 32 + lg * 8) * 2;
            byte ^= (rr & 7) << 4;
            af[f] = *(const short8*)((const char*)As + byte);
        }
#pragma unroll
        for (int g = 0; g < 2; ++g) {
            int col = c0 + g * 16 + lr;
            short8 bf = *(const short8*)&Wt[(size_t)col * DD + s * 32 + lg * 8];
#pragma unroll
            for (int f = 0; f < 4; ++f)
                acc[f][g] = __builtin_amdgcn_mfma_f32_16x16x32_bf16(af[f], bf, acc[f][g], 0, 0, 0);
        }
    }
    float rsv[4][4];
#pragma unroll
    for (int f = 0; f < 4; ++f)
#pragma unroll
        for (int i = 0; i < 4; ++i) {
            int row = r0 + f * 16 + lg * 4 + i;
            rsv[f][i] = (row < NN) ? rs[row] : 0.f;
        }
    float sA[2] = {0.f, 0.f}, qA[2] = {0.f, 0.f};
#pragma unroll
    for (int g = 0; g < 2; ++g) {
        int col = c0 + g * 16 + lr;
        float b = bias[col];
        size_t cb = (size_t)(col >> 1) * pairb + (col & 1) * 2;
#pragma unroll
        for (int f = 0; f < 4; ++f)
#pragma unroll
            for (int i = 0; i < 4; ++i) {
                int row = r0 + f * 16 + lg * 4 + i;
                if (row < NN) {
                    float o = fmaxf(acc[f][g][i] + rsv[f][i] * b, 0.f);
                    *(short*)(C + (size_t)row * rowb + cb) = (short)f2bf(o);
                    sA[g] += o;
                    qA[g] += o * o;
                }
            }
    }
#pragma unroll
    for (int g = 0; g < 2; ++g) {
        sA[g] += __shfl_xor(sA[g], 16);
        sA[g] += __shfl_xor(sA[g], 32);
        qA[g] += __shfl_xor(qA[g], 16);
        qA[g] += __shfl_xor(qA[g], 32);
    }
    if (lg == 0)
#pragma unroll
        for (int g = 0; g < 2; ++g) {
            int col = c0 + g * 16 + lr;
            atomicAdd(&stats_out[col], sA[g]);
            atomicAdd(&stats_out[DD + col], qA[g]);
        }
}

// ---- GAT pair matmul with fused attention; hn written to interleaved layout

template <int PRE>
__global__ __launch_bounds__(256) void mfma_mm_pair(const void* __restrict__ Av,
                                                    const short* __restrict__ Wt1,
                                                    const short* __restrict__ Wt2,
                                                    const float* __restrict__ b1,
                                                    const float* __restrict__ b2,
                                                    const float* __restrict__ a_se,
                                                    const float* __restrict__ a_ne,
                                                    const float* __restrict__ stats_in,
                                                    char* __restrict__ out2base, int rowb,
                                                    int pairb, float* __restrict__ ats_o,
                                                    float* __restrict__ atn_o) {
    __shared__ short As[64 * DD];
    __shared__ float mS[DD], sS[DD];
    int t = threadIdx.x;
    int r0 = blockIdx.x * 64;
    if (PRE == 1) {
        if (t < DD) {
            const float inv_n = 1.0f / (float)NN;
            float m = stats_in[t] * inv_n;
            float var = stats_in[DD + t] * inv_n - m * m;
            mS[t] = m;
            sS[t] = rsqrtf(var + 1e-9f);
        }
        __syncthreads();
    }
    {
        int srow = t >> 2;
        int sk0 = (t & 3) * 32;
        int grow = r0 + srow;
#pragma unroll
        for (int j = 0; j < 4; ++j) {
            int k0 = sk0 + j * 8;
            short8 frag = {0, 0, 0, 0, 0, 0, 0, 0};
            if (grow < NN) {
                if (PRE == 0) {
                    frag = *(const short8*)((const short*)Av + (size_t)grow * DD + k0);
                } else {
                    const float* Ar = (const float*)Av + (size_t)grow * DD;
                    float4 v0 = *(const float4*)(Ar + k0);
                    float4 v1 = *(const float4*)(Ar + k0 + 4);
                    float vv[8] = {v0.x, v0.y, v0.z, v0.w, v1.x, v1.y, v1.z, v1.w};
#pragma unroll
                    for (int e = 0; e < 8; ++e)
                        frag[e] = (short)f2bf((vv[e] - mS[k0 + e]) * sS[k0 + e]);
                }
            }
            int byte = srow * 256 + k0 * 2;
            byte ^= (srow & 7) << 4;
            *(short8*)((char*)As + byte) = frag;
        }
    }
    __syncthreads();
    int w = t >> 6, l = t & 63;
    int c0 = w * 32;
    int lr = l & 15, lg = l >> 4;
    f32x4 acc1[4][2] = {}, acc2[4][2] = {};
#pragma unroll
    for (int s = 0; s < 4; ++s) {
        short8 af[4];
#pragma unroll
        for (int f = 0; f < 4; ++f) {
            int rr = f * 16 + lr;
            int byte = rr * 256 + (s * 32 + lg * 8) * 2;
            byte ^= (rr & 7) << 4;
            af[f] = *(const short8*)((const char*)As + byte);
        }
#pragma unroll
        for (int g = 0; g < 2; ++g) {
            int col = c0 + g * 16 + lr;
            short8 bfa = *(const short8*)&Wt1[(size_t)col * DD + s * 32 + lg * 8];
            short8 bfb = *(const short8*)&Wt2[(size_t)col * DD + s * 32 + lg * 8];
#pragma unroll
            for (int f = 0; f < 4; ++f) {
                acc1[f][g] = __builtin_amdgcn_mfma_f32_16x16x32_bf16(af[f], bfa, acc1[f][g], 0, 0, 0);
                acc2[f][g] = __builtin_amdgcn_mfma_f32_16x16x32_bf16(af[f], bfb, acc2[f][g], 0, 0, 0);
            }
        }
    }
#pragma unroll
    for (int g = 0; g < 2; ++g) {
        int colc = c0 + g * 16 + lr;
        float bb1 = b1[colc], bb2 = b2[colc];
        float asv = a_se[colc], anv = a_ne[colc];
        int h = (c0 >> 4) + g;
        size_t cb = (size_t)(colc >> 1) * pairb + (colc & 1) * 2;
#pragma unroll
        for (int f = 0; f < 4; ++f)
#pragma unroll
            for (int i = 0; i < 4; ++i) {
                int row = r0 + f * 16 + lg * 4 + i;
                float o1 = fmaxf(acc1[f][g][i] + bb1, 0.f);  // hs (ephemeral)
                float o2 = fmaxf(acc2[f][g][i] + bb2, 0.f);  // hn
                if (row < NN) *(short*)(out2base + (size_t)row * rowb + cb) = (short)f2bf(o2);
                float ds = o1 * asv, dn = o1 * anv;
                ds += __shfl_xor(ds, 1);
                dn += __shfl_xor(dn, 1);
                ds += __shfl_xor(ds, 2);
                dn += __shfl_xor(dn, 2);
                ds += __shfl_xor(ds, 4);
                dn += __shfl_xor(dn, 4);
                ds += __shfl_xor(ds, 8);
                dn += __shfl_xor(dn, 8);
                if (lr == 0 && row < NN) {
                    ats_o[row * NH + h] = ds > 0.f ? ds : 0.2f * ds;
                    atn_o[row * NH + h] = dn > 0.f ? dn : 0.2f * dn;
                }
            }
    }
}

// ---------------- fused gather pass A: GAT-L0 + 3x GCN-L0 (G2 dwordx2) ------

__global__ __launch_bounds__(256) void spmm_fusedA(
    const char* __restrict__ G2, const float* __restrict__ ats, const float* __restrict__ atn,
    const int4* __restrict__ ed, const int* __restrict__ row_ptr, float* __restrict__ aggG,
    short* __restrict__ zu, short* __restrict__ zp, short* __restrict__ zf,
    float* __restrict__ rs_all) {
    int r = __builtin_amdgcn_readfirstlane((blockIdx.x * 256 + threadIdx.x) >> 6);
    int lane = threadIdx.x & 63;
    if (r >= NN) return;
    int hh = lane >> 3;
    float a_s = ats[r * NH + hh];
    int start = row_ptr[r], end = row_ptr[r + 1];
    float2 ag = {0.f, 0.f}, au = {0.f, 0.f}, ap = {0.f, 0.f}, af2 = {0.f, 0.f};
    float su = 0.f, sp = 0.f, sf = 0.f;
    int j = start;
    for (; j + 2 <= end; j += 2) {
        int4 a0 = ed[2 * j], b0 = ed[2 * j + 1];
        int4 a1 = ed[2 * j + 2], b1 = ed[2 * j + 3];
        int cA = a0.x, cB = a1.x;
        float at0 = atn[cA * NH + hh], at1 = atn[cB * NH + hh];
        uint2 d0 = *(const uint2*)(G2 + (size_t)cA * 512 + lane * 8);
        uint2 d1 = *(const uint2*)(G2 + (size_t)cB * 512 + lane * 8);
        {
            float vg = __int_as_float(a0.y), vu = __int_as_float(a0.z);
            float vp = __int_as_float(a0.w), vf = __int_as_float(b0.x);
            float e = (a_s + at0) * vg;
            float flo = bflo(d0.x), fhi = bfhi(d0.x), glo = bflo(d0.y), ghi = bfhi(d0.y);
            ag.x += e * glo;  ag.y += e * ghi;
            au.x += vu * flo; au.y += vu * fhi;
            ap.x += vp * flo; ap.y += vp * fhi;
            af2.x += vf * flo; af2.y += vf * fhi;
            su += vu; sp += vp; sf += vf;
        }
        {
            float vg = __int_as_float(a1.y), vu = __int_as_float(a1.z);
            float vp = __int_as_float(a1.w), vf = __int_as_float(b1.x);
            float e = (a_s + at1) * vg;
            float flo = bflo(d1.x), fhi = bfhi(d1.x), glo = bflo(d1.y), ghi = bfhi(d1.y);
            ag.x += e * glo;  ag.y += e * ghi;
            au.x += vu * flo; au.y += vu * fhi;
            ap.x += vp * flo; ap.y += vp * fhi;
            af2.x += vf * flo; af2.y += vf * fhi;
            su += vu; sp += vp; sf += vf;
        }
    }
    if (j < end) {
        int4 a0 = ed[2 * j], b0 = ed[2 * j + 1];
        int cA = a0.x;
        float at0 = atn[cA * NH + hh];
        uint2 d0 = *(const uint2*)(G2 + (size_t)cA * 512 + lane * 8);
        float vg = __int_as_float(a0.y), vu = __int_as_float(a0.z);
        float vp = __int_as_float(a0.w), vf = __int_as_float(b0.x);
        float e = (a_s + at0) * vg;
        float flo = bflo(d0.x), fhi = bfhi(d0.x), glo = bflo(d0.y), ghi = bfhi(d0.y);
        ag.x += e * glo;  ag.y += e * ghi;
        au.x += vu * flo; au.y += vu * fhi;
        ap.x += vp * flo; ap.y += vp * fhi;
        af2.x += vf * flo; af2.y += vf * fhi;
        su += vu; sp += vp; sf += vf;
    }
    size_t o = (size_t)r * DD + lane * 2;
    *(float2*)&aggG[o] = ag;
    *(unsigned int*)(zu + o) = pack2bf(au.x, au.y);
    *(unsigned int*)(zp + o) = pack2bf(ap.x, ap.y);
    *(unsigned int*)(zf + o) = pack2bf(af2.x, af2.y);
    if (lane == 0) {
        rs_all[r] = su;
        rs_all[NN + r] = sp;
        rs_all[2 * NN + r] = sf;
    }
}

// ---------------- fused gather pass B: GAT-L1 + 3x GCN-L1 (G4 dwordx4) ------

__global__ __launch_bounds__(256) void spmm_fusedB(
    const char* __restrict__ G4, const float* __restrict__ ats, const float* __restrict__ atn,
    const int4* __restrict__ ed, const int* __restrict__ row_ptr, float* __restrict__ aggG,
    short* __restrict__ z1u, short* __restrict__ z1p, short* __restrict__ z1f) {
    int r = __builtin_amdgcn_readfirstlane((blockIdx.x * 256 + threadIdx.x) >> 6);
    int lane = threadIdx.x & 63;
    if (r >= NN) return;
    int hh = lane >> 3;
    float a_s = ats[r * NH + hh];
    int start = row_ptr[r], end = row_ptr[r + 1];
    float2 ag = {0.f, 0.f}, au = {0.f, 0.f}, ap = {0.f, 0.f}, af2 = {0.f, 0.f};
    int j = start;
    for (; j + 2 <= end; j += 2) {
        int4 a0 = ed[2 * j], b0 = ed[2 * j + 1];
        int4 a1 = ed[2 * j + 2], b1 = ed[2 * j + 3];
        int cA = a0.x, cB = a1.x;
        float at0 = atn[cA * NH + hh], at1 = atn[cB * NH + hh];
        uint4 d0 = *(const uint4*)(G4 + (size_t)cA * 1024 + lane * 16);
        uint4 d1 = *(const uint4*)(G4 + (size_t)cB * 1024 + lane * 16);
        float e0 = (a_s + at0) * __int_as_float(a0.y);
        float e1 = (a_s + at1) * __int_as_float(a1.y);
        float vu0 = __int_as_float(a0.z), vp0 = __int_as_float(a0.w), vf0 = __int_as_float(b0.x);
        float vu1 = __int_as_float(a1.z), vp1 = __int_as_float(a1.w), vf1 = __int_as_float(b1.x);
        ag.x += e0 * bflo(d0.x) + e1 * bflo(d1.x);
        ag.y += e0 * bfhi(d0.x) + e1 * bfhi(d1.x);
        au.x += vu0 * bflo(d0.y) + vu1 * bflo(d1.y);
        au.y += vu0 * bfhi(d0.y) + vu1 * bfhi(d1.y);
        ap.x += vp0 * bflo(d0.z) + vp1 * bflo(d1.z);
        ap.y += vp0 * bfhi(d0.z) + vp1 * bfhi(d1.z);
        af2.x += vf0 * bflo(d0.w) + vf1 * bflo(d1.w);
        af2.y += vf0 * bfhi(d0.w) + vf1 * bfhi(d1.w);
    }
    if (j < end) {
        int4 a0 = ed[2 * j], b0 = ed[2 * j + 1];
        int cA = a0.x;
        float at0 = atn[cA * NH + hh];
        uint4 d0 = *(const uint4*)(G4 + (size_t)cA * 1024 + lane * 16);
        float e0 = (a_s + at0) * __int_as_float(a0.y);
        float vu0 = __int_as_float(a0.z), vp0 = __int_as_float(a0.w), vf0 = __int_as_float(b0.x);
        ag.x += e0 * bflo(d0.x);
        ag.y += e0 * bfhi(d0.x);
        au.x += vu0 * bflo(d0.y);
        au.y += vu0 * bfhi(d0.y);
        ap.x += vp0 * bflo(d0.z);
        ap.y += vp0 * bfhi(d0.z);
        af2.x += vf0 * bflo(d0.w);
        af2.y += vf0 * bfhi(d0.w);
    }
    size_t o = (size_t)r * DD + lane * 2;
    *(float2*)&aggG[o] = ag;
    *(unsigned int*)(z1u + o) = pack2bf(au.x, au.y);
    *(unsigned int*)(z1p + o) = pack2bf(ap.x, ap.y);
    *(unsigned int*)(z1f + o) = pack2bf(af2.x, af2.y);
}

// ---------------- classifier (fp32 input; GAT/self) ----------------

template <bool FIRST>
__global__ __launch_bounds__(256) void cls_acc_kernel(const float* __restrict__ o,
                                                      const float* __restrict__ Wc,
                                                      const float* __restrict__ stats,
                                                      const float* __restrict__ b_cls,
                                                      float* __restrict__ out) {
    __shared__ float Wl[DD * NCLS];
    __shared__ float mS[DD], sS[DD];
    int t = threadIdx.x;
    for (int i = t; i < DD * NCLS; i += 256) Wl[i] = Wc[i];
    if (t < DD) {
        const float inv_n = 1.0f / (float)NN;
        float m = stats[t] * inv_n;
        float var = stats[DD + t] * inv_n - m * m;
        mS[t] = m;
        sS[t] = rsqrtf(var + 1e-9f);
    }
    __syncthreads();
    int n = blockIdx.x * 256 + t;
    if (n >= NN) return;
    float acc[NCLS] = {};
    const float4* orow = (const float4*)(o + (size_t)n * DD);
    for (int k4 = 0; k4 < DD / 4; ++k4) {
        float4 v = orow[k4];
#pragma unroll
        for (int kk = 0; kk < 4; ++kk) {
            int k = k4 * 4 + kk;
            float a = (((const float*)&v)[kk] - mS[k]) * sS[k];
#pragma unroll
            for (int c = 0; c < NCLS; ++c) acc[c] += a * Wl[k * NCLS + c];
        }
    }
#pragma unroll
    for (int c = 0; c < NCLS; ++c) {
        if (FIRST)
            out[n * NCLS + c] = acc[c] + b_cls[c];
        else
            out[n * NCLS + c] += acc[c];
    }
}

// ---- batched GCN classifier (bf16 y1, BN via stats; atomic accumulate) ----

struct CLS3 {
    const short* o[3];
    const float* stats[3];
};

__global__ __launch_bounds__(256) void cls3_kernel(CLS3 a, const float* __restrict__ W_cls,
                                                   float* __restrict__ out) {
    int br = blockIdx.y;
    const short* o = a.o[br];
    const float* st = a.stats[br];
    const float* Wc = W_cls + (size_t)(DD + DD * br) * NCLS;
    __shared__ float Wl[DD * NCLS];
    __shared__ float mS[DD], sS[DD];
    int t = threadIdx.x;
    for (int i = t; i < DD * NCLS; i += 256) Wl[i] = Wc[i];
    if (t < DD) {
        const float inv_n = 1.0f / (float)NN;
        float m = st[t] * inv_n;
        float var = st[DD + t] * inv_n - m * m;
        mS[t] = m;
        sS[t] = rsqrtf(var + 1e-9f);
    }
    __syncthreads();
    int n = blockIdx.x * 256 + t;
    if (n >= NN) return;
    float acc[NCLS] = {};
    const uint4* orow = (const uint4*)(o + (size_t)n * DD);
    for (int k8 = 0; k8 < DD / 8; ++k8) {
        uint4 v = orow[k8];
        float vv[8] = {bflo(v.x), bfhi(v.x), bflo(v.y), bfhi(v.y),
                       bflo(v.z), bfhi(v.z), bflo(v.w), bfhi(v.w)};
#pragma unroll
        for (int kk = 0; kk < 8; ++kk) {
            int k = k8 * 8 + kk;
            float a2 = (vv[kk] - mS[k]) * sS[k];
#pragma unroll
            for (int c = 0; c < NCLS; ++c) acc[c] += a2 * Wl[k * NCLS + c];
        }
    }
#pragma unroll
    for (int c = 0; c < NCLS; ++c) atomicAdd(&out[n * NCLS + c], acc[c]);
}

// ---------------------------------------------------------------------------

extern "C" void kernel_launch(void* const* d_in, const int* in_sizes, int n_in, void* d_out,
                              int out_size, void* d_ws, size_t ws_size, hipStream_t stream) {
    const float* f_in = (const float*)d_in[0];
    const int* edge_row = (const int*)d_in[1];
    const int* edge_col = (const int*)d_in[2];
    const float* vals_gat = (const float*)d_in[3];
    const float* vals_uttr = (const float*)d_in[4];
    const float* vals_past = (const float*)d_in[5];
    const float* vals_futr = (const float*)d_in[6];
    const float* gat_Ws = (const float*)d_in[7];
    const float* gat_bs = (const float*)d_in[8];
    const float* gat_Wn = (const float*)d_in[9];
    const float* gat_bn = (const float*)d_in[10];
    const float* gat_as = (const float*)d_in[11];
    const float* gat_an = (const float*)d_in[12];
    const float* W_uttr = (const float*)d_in[13];
    const float* b_uttr = (const float*)d_in[14];
    const float* W_past = (const float*)d_in[15];
    const float* b_past = (const float*)d_in[16];
    const float* W_futr = (const float*)d_in[17];
    const float* b_futr = (const float*)d_in[18];
    const float* W_self = (const float*)d_in[19];
    const float* b_self = (const float*)d_in[20];
    const float* W_cls = (const float*)d_in[21];
    const float* b_cls = (const float*)d_in[22];
    float* out = (float*)d_out;

    char* ws = (char*)d_ws;
    size_t off = 0;
    auto alloc = [&](size_t bytes) -> void* {
        void* p = ws + off;
        off = (off + bytes + 255) & ~(size_t)255;
        return p;
    };
    float* stats_all = (float*)alloc(9 * 2 * DD * 4);
    int* cnt = (int*)alloc((size_t)NN * 4);  // adjacent to stats -> one memset
    float* tmp1 = (float*)alloc((size_t)NN * DD * 4);  // self h; later z1p/z1f
    float* bufA = (float*)alloc((size_t)NN * DD * 4);  // GAT agg L0/L1
    short* fbf = (short*)alloc((size_t)NN * DD * 2);   // f_in bf16; later z1u
    char* G2 = (char*)alloc((size_t)NN * 512);         // [node][lane][fbf,hnL0]
    char* G4 = (char*)alloc((size_t)NN * 1024);        // [node][lane][hnL1,y0u,y0p,y0f]
    short* z0u = (short*)alloc((size_t)NN * DD * 2);   // z0; later y1
    short* z0p = (short*)alloc((size_t)NN * DD * 2);
    short* z0f = (short*)alloc((size_t)NN * DD * 2);
    float* rs_all = (float*)alloc((size_t)3 * NN * 4);
    float* ats_b = (float*)alloc((size_t)NN * NH * 4);
    float* atn_b = (float*)alloc((size_t)NN * NH * 4);
    short* Wt_all = (short*)alloc((size_t)14 * DD * DD * 2);
    float* bfix = (float*)alloc((size_t)3 * DD * 4);
    int* row_ptr = (int*)alloc((size_t)(NN + 1) * 4);
    int* fill = (int*)alloc((size_t)NN * 4);
    int* pre_b = (int*)alloc((size_t)NN * 4);
    int* bsum = (int*)alloc((size_t)SCAN_B * 4);
    int* boff = (int*)alloc((size_t)257 * 4);
    int4* ed = (int4*)alloc((size_t)NE * 32);

    auto stats = [&](int s) { return stats_all + (size_t)s * 2 * DD; };
    auto Wt = [&](int w) { return Wt_all + (size_t)w * DD * DD; };
    // stats: 0=GAT L0 agg, 1=GAT L1 agg, 2..4=GCN y0, 5..7=GCN y1, 8=self

    const int gE = (NE + 255) / 256;
    const int gMM = (NN + 63) / 64;
    const int gSP = NN / 4;  // exact (NN % 4 == 0)
    const int gCA = (NN + 255) / 256;
    const int gBF = (NN * DD / 8 + 255) / 256;

    hipMemsetAsync(stats_all, 0, 9 * 2 * DD * 4 + (size_t)NN * 4, stream);

    // CSR build
    count_kernel<<<gE, 256, 0, stream>>>(edge_row, cnt);
    scan1_kernel<<<SCAN_B, 256, 0, stream>>>(cnt, pre_b, bsum);
    scan2_kernel<<<1, 256, 0, stream>>>(bsum, boff);
    scan3_kernel<<<SCAN_B, 256, 0, stream>>>(pre_b, boff, row_ptr, fill);
    scatter_kernel<<<gE, 256, 0, stream>>>(edge_row, edge_col, vals_gat, vals_uttr, vals_past,
                                           vals_futr, fill, ed);

    tobf16_kernel<<<gBF, 256, 0, stream>>>(f_in, fbf, G2);

    WPrepArgs wa;
    wa.src[0] = gat_Ws;
    wa.src[1] = gat_Wn;
    wa.src[2] = gat_Ws + (size_t)DD * DD;
    wa.src[3] = gat_Wn + (size_t)DD * DD;
    wa.src[4] = W_uttr;
    wa.src[5] = W_uttr + (size_t)DD * DD;  // unused slot
    wa.src[6] = W_past;
    wa.src[7] = W_past + (size_t)DD * DD;  // unused slot
    wa.src[8] = W_futr;
    wa.src[9] = W_futr + (size_t)DD * DD;  // unused slot
    wa.src[10] = W_self;
    wprep_kernel<<<(11 * DD * DD + 255) / 256, 256, 0, stream>>>(wa, Wt_all);

    // ---- self branch (FIRST classifier write) ----
    mfma_mm_self<<<gMM, 256, 0, stream>>>(fbf, Wt(10), b_self, stats(8), tmp1);
    cls_acc_kernel<true><<<gCA, 256, 0, stream>>>(tmp1, W_cls + (size_t)4 * DD * NCLS, stats(8),
                                                  b_cls, out);

    // ---- GAT L0 (hn -> G2 slice 1) + fused gather A ----
    mfma_mm_pair<0><<<gMM, 256, 0, stream>>>(fbf, Wt(0), Wt(1), gat_bs, gat_bn, gat_as, gat_an,
                                             nullptr, G2 + 4, 512, 8, ats_b, atn_b);
    spmm_fusedA<<<gSP, 256, 0, stream>>>(G2, ats_b, atn_b, ed, row_ptr, bufA, z0u, z0p, z0f,
                                         rs_all);
    bn_stats_kernel<<<256, 256, 0, stream>>>(bufA, stats(0));

    // ---- GAT L1 matmul (BN on the fly; hn -> G4 slice 0) ----
    mfma_mm_pair<1><<<gMM, 256, 0, stream>>>(bufA, Wt(2), Wt(3), gat_bs + DD, gat_bn + DD,
                                             gat_as + DD, gat_an + DD, stats(0), G4, 1024, 16,
                                             ats_b, atn_b);

    // ---- GCN L0 matmuls (batched, z0 -> y0 into G4 slices 1..3) ----
    const float* bb[3] = {b_uttr, b_past, b_futr};
    const float* Worig[3] = {W_uttr, W_past, W_futr};
    short* z0a[3] = {z0u, z0p, z0f};
    MMB m0;
    for (int br = 0; br < 3; ++br) {
        m0.A[br] = z0a[br];
        m0.W[br] = Wt(4 + br * 2);
        m0.bias[br] = bb[br];
        m0.rs[br] = rs_all + (size_t)br * NN;
        m0.stats[br] = stats(2 + br);
        m0.C[br] = G4 + 4 + br * 4;
    }
    m0.rowb = 1024;
    m0.pairb = 16;
    mfma_mm_gcn<<<dim3(gMM, 3), 256, 0, stream>>>(m0);

    // ---- wfix: fold BN(y0) into L1 weights ----
    WFixArgs wf;
    for (int br = 0; br < 3; ++br) {
        wf.W1[br] = Worig[br] + (size_t)DD * DD;
        wf.b1[br] = bb[br] + DD;
        wf.stats[br] = stats(2 + br);
    }
    wfix_kernel<<<2, 256, 0, stream>>>(wf, Wt(11), bfix);

    // ---- fused gather B: GAT-L1 agg + 3x GCN z1 ----
    short* z1u = fbf;           // fbf dead
    short* z1p = (short*)tmp1;  // tmp1 dead after self cls
    short* z1f = (short*)tmp1 + (size_t)NN * DD;
    spmm_fusedB<<<gSP, 256, 0, stream>>>(G4, ats_b, atn_b, ed, row_ptr, bufA, z1u, z1p, z1f);
    bn_stats_kernel<<<256, 256, 0, stream>>>(bufA, stats(1));
    cls_acc_kernel<false><<<gCA, 256, 0, stream>>>(bufA, W_cls, stats(1), b_cls, out);

    // ---- GCN L1 matmuls (batched, z1 -> y1 plain bf16 in z0 slots) ----
    MMB m1;
    short* z1a[3] = {z1u, z1p, z1f};
    for (int br = 0; br < 3; ++br) {
        m1.A[br] = z1a[br];
        m1.W[br] = Wt(11 + br);
        m1.bias[br] = bfix + (size_t)br * DD;
        m1.rs[br] = rs_all + (size_t)br * NN;
        m1.stats[br] = stats(5 + br);
        m1.C[br] = (char*)z0a[br];
    }
    m1.rowb = 256;
    m1.pairb = 4;
    mfma_mm_gcn<<<dim3(gMM, 3), 256, 0, stream>>>(m1);

    // ---- batched GCN classifiers ----
    CLS3 c3;
    for (int br = 0; br < 3; ++br) {
        c3.o[br] = z0a[br];
        c3.stats[br] = stats(5 + br);
    }
    cls3_kernel<<<dim3(gCA, 3), 256, 0, stream>>>(c3, W_cls, out);
}

// Round 10
// 543.657 us; speedup vs baseline: 1.9193x; 1.1012x over previous
//
#include <hip/hip_runtime.h>
#include <hip/hip_bf16.h>

// ---------------------------------------------------------------------------
// ERCGNN R10: revert to R5 structure (best measured, 573us). Changes:
// 16B packed edge records (col u16 + 4x bf16 vals, single dwordx4/edge),
// vectorized bn_stats (float4 + LDS-staged atomics), batched GCN classifiers.
// G2/G4 interleave dropped (R9: gather BW-bound, producer write-amp 4x).
// ---------------------------------------------------------------------------

#define NN 50000
#define NE 500000
#define DD 128
#define NH 8
#define DHD 16
#define NCLS 7
#define SCAN_B 196  // ceil(50000/256)

typedef __attribute__((ext_vector_type(8))) short short8;
typedef __attribute__((ext_vector_type(4))) float f32x4;

__device__ __forceinline__ unsigned short f2bf(float x) {
    unsigned int u = __float_as_uint(x);
    unsigned int r = (u + 0x7fffu + ((u >> 16) & 1u)) >> 16;  // RNE
    return (unsigned short)r;
}
__device__ __forceinline__ unsigned int pack2bf(float lo, float hi) {
    return (unsigned int)f2bf(lo) | ((unsigned int)f2bf(hi) << 16);
}
__device__ __forceinline__ float bflo(unsigned int u) { return __uint_as_float(u << 16); }
__device__ __forceinline__ float bfhi(unsigned int u) { return __uint_as_float(u & 0xffff0000u); }

// ---------------- CSR build ----------------

__global__ void count_kernel(const int* __restrict__ row, int* __restrict__ cnt) {
    int e = blockIdx.x * 256 + threadIdx.x;
    if (e < NE) atomicAdd(&cnt[row[e]], 1);
}

__global__ __launch_bounds__(256) void scan1_kernel(const int* __restrict__ cnt,
                                                    int* __restrict__ pre,
                                                    int* __restrict__ bsum) {
    __shared__ int s[256];
    int t = threadIdx.x;
    int i = blockIdx.x * 256 + t;
    int v = (i < NN) ? cnt[i] : 0;
    s[t] = v;
    __syncthreads();
    for (int off = 1; off < 256; off <<= 1) {
        int u = (t >= off) ? s[t - off] : 0;
        __syncthreads();
        s[t] += u;
        __syncthreads();
    }
    if (i < NN) pre[i] = s[t] - v;
    if (t == 255) bsum[blockIdx.x] = s[255];
}

__global__ __launch_bounds__(256) void scan2_kernel(const int* __restrict__ bsum,
                                                    int* __restrict__ boff) {
    __shared__ int s[256];
    int t = threadIdx.x;
    int v = (t < SCAN_B) ? bsum[t] : 0;
    s[t] = v;
    __syncthreads();
    for (int off = 1; off < 256; off <<= 1) {
        int u = (t >= off) ? s[t - off] : 0;
        __syncthreads();
        s[t] += u;
        __syncthreads();
    }
    boff[t] = s[t] - v;
    if (t == 255) boff[256] = s[255];
}

__global__ __launch_bounds__(256) void scan3_kernel(const int* __restrict__ pre,
                                                    const int* __restrict__ boff,
                                                    int* __restrict__ row_ptr,
                                                    int* __restrict__ fill) {
    int t = threadIdx.x;
    int i = blockIdx.x * 256 + t;
    if (i < NN) {
        int v = pre[i] + boff[blockIdx.x];
        row_ptr[i] = v;
        fill[i] = v;
    }
    if (blockIdx.x == 0 && t == 0) row_ptr[NN] = boff[256];
}

// 16B edge record: {col | vg<<16, vu | vp<<16, vf, pad}; col < 65536.
__global__ void scatter_kernel(const int* __restrict__ row, const int* __restrict__ col,
                               const float* __restrict__ vg, const float* __restrict__ vu,
                               const float* __restrict__ vp, const float* __restrict__ vf,
                               int* __restrict__ fill, int4* __restrict__ ed) {
    int e = blockIdx.x * 256 + threadIdx.x;
    if (e >= NE) return;
    int r = row[e];
    int pos = atomicAdd(&fill[r], 1);
    unsigned int x = (unsigned int)col[e] | ((unsigned int)f2bf(vg[e]) << 16);
    unsigned int y = (unsigned int)f2bf(vu[e]) | ((unsigned int)f2bf(vp[e]) << 16);
    unsigned int z = (unsigned int)f2bf(vf[e]);
    ed[pos] = make_int4((int)x, (int)y, (int)z, 0);
}

// ---------------- fp32 -> bf16 ----------------

__global__ __launch_bounds__(256) void tobf16_kernel(const float* __restrict__ x,
                                                     short* __restrict__ y) {
    int idx = blockIdx.x * 256 + threadIdx.x;
    if (idx >= NN * DD / 8) return;
    float4 a = ((const float4*)x)[idx * 2];
    float4 b = ((const float4*)x)[idx * 2 + 1];
    uint4 o;
    o.x = pack2bf(a.x, a.y);
    o.y = pack2bf(a.z, a.w);
    o.z = pack2bf(b.x, b.y);
    o.w = pack2bf(b.z, b.w);
    *(uint4*)(y + (size_t)idx * 8) = o;
}

// ---------------- weight prep ----------------

struct WPrepArgs {
    const float* src[11];
};

__global__ __launch_bounds__(256) void wprep_kernel(WPrepArgs a, short* __restrict__ out) {
    int idx = blockIdx.x * 256 + threadIdx.x;
    if (idx >= 11 * DD * DD) return;
    int w = idx >> 14;
    int r = idx & 16383;
    int n = r >> 7, k = r & 127;
    const float* W = a.src[w];
    float v = (w < 4) ? W[(size_t)((n >> 4) * DD + k) * DHD + (n & 15)] : W[(size_t)k * DD + n];
    out[idx] = (short)f2bf(v);
}

// ---- wfix: fold BN(y0) into L1 weights ----

struct WFixArgs {
    const float* W1[3];
    const float* b1[3];
    const float* stats[3];
};

__global__ __launch_bounds__(256) void wfix_kernel(WFixArgs a, short* __restrict__ wt_out,
                                                   float* __restrict__ bfix) {
    int idx = blockIdx.x * 256 + threadIdx.x;
    if (idx >= 3 * DD) return;
    int br = idx >> 7, n = idx & 127;
    const float* st = a.stats[br];
    const float* W = a.W1[br];
    const float inv_n = 1.0f / (float)NN;
    float accb = 0.f;
    short* wo = wt_out + (size_t)br * DD * DD + (size_t)n * DD;
#pragma unroll 4
    for (int k = 0; k < DD; ++k) {
        float m = st[k] * inv_n;
        float var = st[DD + k] * inv_n - m * m;
        float s = rsqrtf(var + 1e-9f);
        float w = W[(size_t)k * DD + n];
        wo[k] = (short)f2bf(s * w);
        accb += m * s * w;
    }
    bfix[idx] = a.b1[br][n] - accb;
}

// ---------------- BN stats (vectorized, LDS-staged atomics) ----------------

__global__ __launch_bounds__(256) void bn_stats_kernel(const float* __restrict__ x,
                                                       float* __restrict__ stats) {
    __shared__ float sred[2 * DD];
    int t = threadIdx.x;
    sred[t] = 0.f;
    __syncthreads();
    int c4 = t & 31;   // float4 index within row
    int sub = t >> 5;  // 8 row phases
    int rows_per_block = (NN + gridDim.x - 1) / gridDim.x;
    int rbeg = blockIdx.x * rows_per_block;
    int rend = min(rbeg + rows_per_block, NN);
    float s[4] = {}, q[4] = {};
    for (int r = rbeg + sub; r < rend; r += 8) {
        float4 v = *(const float4*)&x[(size_t)r * DD + c4 * 4];
        s[0] += v.x; q[0] += v.x * v.x;
        s[1] += v.y; q[1] += v.y * v.y;
        s[2] += v.z; q[2] += v.z * v.z;
        s[3] += v.w; q[3] += v.w * v.w;
    }
#pragma unroll
    for (int i = 0; i < 4; ++i) {
        s[i] += __shfl_xor(s[i], 32);
        q[i] += __shfl_xor(q[i], 32);
    }
    if ((t & 32) == 0) {
#pragma unroll
        for (int i = 0; i < 4; ++i) {
            atomicAdd(&sred[c4 * 4 + i], s[i]);
            atomicAdd(&sred[DD + c4 * 4 + i], q[i]);
        }
    }
    __syncthreads();
    atomicAdd(&stats[t], sred[t]);
}

// ---------------- self matmul: bf16 A -> fp32 relu C, stats ----------------

__global__ __launch_bounds__(256) void mfma_mm_self(const short* __restrict__ A,
                                                    const short* __restrict__ Wt,
                                                    const float* __restrict__ bias,
                                                    float* __restrict__ stats_out,
                                                    float* __restrict__ C) {
    __shared__ short As[64 * DD];
    int t = threadIdx.x;
    int r0 = blockIdx.x * 64;
    {
        int srow = t >> 2;
        int sk0 = (t & 3) * 32;
        int grow = r0 + srow;
#pragma unroll
        for (int j = 0; j < 4; ++j) {
            int k0 = sk0 + j * 8;
            short8 frag = {0, 0, 0, 0, 0, 0, 0, 0};
            if (grow < NN) frag = *(const short8*)(A + (size_t)grow * DD + k0);
            int byte = srow * 256 + k0 * 2;
            byte ^= (srow & 7) << 4;
            *(short8*)((char*)As + byte) = frag;
        }
    }
    __syncthreads();
    int w = t >> 6, l = t & 63;
    int c0 = w * 32;
    int lr = l & 15, lg = l >> 4;
    f32x4 acc[4][2] = {};
#pragma unroll
    for (int s = 0; s < 4; ++s) {
        short8 af[4];
#pragma unroll
        for (int f = 0; f < 4; ++f) {
            int rr = f * 16 + lr;
            int byte = rr * 256 + (s * 32 + lg * 8) * 2;
            byte ^= (rr & 7) << 4;
            af[f] = *(const short8*)((const char*)As + byte);
        }
#pragma unroll
        for (int g = 0; g < 2; ++g) {
            int col = c0 + g * 16 + lr;
            short8 bf = *(const short8*)&Wt[(size_t)col * DD + s * 32 + lg * 8];
#pragma unroll
            for (int f = 0; f < 4; ++f)
                acc[f][g] = __builtin_amdgcn_mfma_f32_16x16x32_bf16(af[f], bf, acc[f][g], 0, 0, 0);
        }
    }
    float sA[2] = {0.f, 0.f}, qA[2] = {0.f, 0.f};
#pragma unroll
    for (int g = 0; g < 2; ++g) {
        int col = c0 + g * 16 + lr;
        float b = bias[col];
#pragma unroll
        for (int f = 0; f < 4; ++f)
#pragma unroll
            for (int i = 0; i < 4; ++i) {
                int row = r0 + f * 16 + lg * 4 + i;
                if (row < NN) {
                    float o = fmaxf(acc[f][g][i] + b, 0.f);
                    C[(size_t)row * DD + col] = o;
                    sA[g] += o;
                    qA[g] += o * o;
                }
            }
    }
#pragma unroll
    for (int g = 0; g < 2; ++g) {
        sA[g] += __shfl_xor(sA[g], 16);
        sA[g] += __shfl_xor(sA[g], 32);
        qA[g] += __shfl_xor(qA[g], 16);
        qA[g] += __shfl_xor(qA[g], 32);
    }
    if (lg == 0)
#pragma unroll
        for (int g = 0; g < 2; ++g) {
            int col = c0 + g * 16 + lr;
            atomicAdd(&stats_out[col], sA[g]);
            atomicAdd(&stats_out[DD + col], qA[g]);
        }
}

// ---- batched GCN matmul: y = relu(A@W + rs*bias) -> bf16, stats of y ----

struct MMB {
    const short* A[3];
    const short* W[3];
    const float* bias[3];
    const float* rs[3];
    float* stats[3];
    short* C[3];
};

__global__ __launch_bounds__(256) void mfma_mm_gcn(MMB m) {
    int br = blockIdx.y;
    const short* A = m.A[br];
    const short* Wt = m.W[br];
    const float* bias = m.bias[br];
    const float* rs = m.rs[br];
    float* stats_out = m.stats[br];
    short* C = m.C[br];

    __shared__ short As[64 * DD];
    int t = threadIdx.x;
    int r0 = blockIdx.x * 64;
    {
        int srow = t >> 2;
        int sk0 = (t & 3) * 32;
        int grow = r0 + srow;
#pragma unroll
        for (int j = 0; j < 4; ++j) {
            int k0 = sk0 + j * 8;
            short8 frag = {0, 0, 0, 0, 0, 0, 0, 0};
            if (grow < NN) frag = *(const short8*)(A + (size_t)grow * DD + k0);
            int byte = srow * 256 + k0 * 2;
            byte ^= (srow & 7) << 4;
            *(short8*)((char*)As + byte) = frag;
        }
    }
    __syncthreads();
    int w = t >> 6, l = t & 63;
    int c0 = w * 32;
    int lr = l & 15, lg = l >> 4;
    f32x4 acc[4][2] = {};
#pragma unroll
    for (int s = 0; s < 4; ++s) {
        short8 af[4];
#pragma unroll
        for (int f = 0; f < 4; ++f) {
            int rr = f * 16 + lr;
            int byte = rr * 256 + (s * 32 + lg * 8) * 2;
            byte ^= (rr & 7) << 4;
            af[f] = *(const short8*)((const char*)As + byte);
        }
#pragma unroll
        for (int g = 0; g < 2; ++g) {
            int col = c0 + g * 16 + lr;
            short8 bf = *(const short8*)&Wt[(size_t)col * DD + s * 32 + lg * 8];
#pragma unroll
            for (int f = 0; f < 4; ++f)
                acc[f][g] = __builtin_amdgcn_mfma_f32_16x16x32_bf16(af[f], bf, acc[f][g], 0, 0, 0);
        }
    }
    float rsv[4][4];
#pragma unroll
    for (int f = 0; f < 4; ++f)
#pragma unroll
        for (int i = 0; i < 4; ++i) {
            int row = r0 + f * 16 + lg * 4 + i;
            rsv[f][i] = (row < NN) ? rs[row] : 0.f;
        }
    float sA[2] = {0.f, 0.f}, qA[2] = {0.f, 0.f};
#pragma unroll
    for (int g = 0; g < 2; ++g) {
        int col = c0 + g * 16 + lr;
        float b = bias[col];
#pragma unroll
        for (int f = 0; f < 4; ++f)
#pragma unroll
            for (int i = 0; i < 4; ++i) {
                int row = r0 + f * 16 + lg * 4 + i;
                if (row < NN) {
                    float o = fmaxf(acc[f][g][i] + rsv[f][i] * b, 0.f);
                    C[(size_t)row * DD + col] = (short)f2bf(o);
                    sA[g] += o;
                    qA[g] += o * o;
                }
            }
    }
#pragma unroll
    for (int g = 0; g < 2; ++g) {
        sA[g] += __shfl_xor(sA[g], 16);
        sA[g] += __shfl_xor(sA[g], 32);
        qA[g] += __shfl_xor(qA[g], 16);
        qA[g] += __shfl_xor(qA[g], 32);
    }
    if (lg == 0)
#pragma unroll
        for (int g = 0; g < 2; ++g) {
            int col = c0 + g * 16 + lr;
            atomicAdd(&stats_out[col], sA[g]);
            atomicAdd(&stats_out[DD + col], qA[g]);
        }
}

// ---- GAT pair matmul with fused attention ----
// PRE: 0 = A bf16; 1 = A fp32 with BN(stats_in).

template <int PRE>
__global__ __launch_bounds__(256) void mfma_mm_pair(const void* __restrict__ Av,
                                                    const short* __restrict__ Wt1,
                                                    const short* __restrict__ Wt2,
                                                    const float* __restrict__ b1,
                                                    const float* __restrict__ b2,
                                                    const float* __restrict__ a_se,
                                                    const float* __restrict__ a_ne,
                                                    const float* __restrict__ stats_in,
                                                    short* __restrict__ out2,
                                                    float* __restrict__ ats_o,
                                                    float* __restrict__ atn_o) {
    __shared__ short As[64 * DD];
    __shared__ float mS[DD], sS[DD];
    int t = threadIdx.x;
    int r0 = blockIdx.x * 64;
    if (PRE == 1) {
        if (t < DD) {
            const float inv_n = 1.0f / (float)NN;
            float m = stats_in[t] * inv_n;
            float var = stats_in[DD + t] * inv_n - m * m;
            mS[t] = m;
            sS[t] = rsqrtf(var + 1e-9f);
        }
        __syncthreads();
    }
    {
        int srow = t >> 2;
        int sk0 = (t & 3) * 32;
        int grow = r0 + srow;
#pragma unroll
        for (int j = 0; j < 4; ++j) {
            int k0 = sk0 + j * 8;
            short8 frag = {0, 0, 0, 0, 0, 0, 0, 0};
            if (grow < NN) {
                if (PRE == 0) {
                    frag = *(const short8*)((const short*)Av + (size_t)grow * DD + k0);
                } else {
                    const float* Ar = (const float*)Av + (size_t)grow * DD;
                    float4 v0 = *(const float4*)(Ar + k0);
                    float4 v1 = *(const float4*)(Ar + k0 + 4);
                    float vv[8] = {v0.x, v0.y, v0.z, v0.w, v1.x, v1.y, v1.z, v1.w};
#pragma unroll
                    for (int e = 0; e < 8; ++e)
                        frag[e] = (short)f2bf((vv[e] - mS[k0 + e]) * sS[k0 + e]);
                }
            }
            int byte = srow * 256 + k0 * 2;
            byte ^= (srow & 7) << 4;
            *(short8*)((char*)As + byte) = frag;
        }
    }
    __syncthreads();
    int w = t >> 6, l = t & 63;
    int c0 = w * 32;
    int lr = l & 15, lg = l >> 4;
    f32x4 acc1[4][2] = {}, acc2[4][2] = {};
#pragma unroll
    for (int s = 0; s < 4; ++s) {
        short8 af[4];
#pragma unroll
        for (int f = 0; f < 4; ++f) {
            int rr = f * 16 + lr;
            int byte = rr * 256 + (s * 32 + lg * 8) * 2;
            byte ^= (rr & 7) << 4;
            af[f] = *(const short8*)((const char*)As + byte);
        }
#pragma unroll
        for (int g = 0; g < 2; ++g) {
            int col = c0 + g * 16 + lr;
            short8 bfa = *(const short8*)&Wt1[(size_t)col * DD + s * 32 + lg * 8];
            short8 bfb = *(const short8*)&Wt2[(size_t)col * DD + s * 32 + lg * 8];
#pragma unroll
            for (int f = 0; f < 4; ++f) {
                acc1[f][g] = __builtin_amdgcn_mfma_f32_16x16x32_bf16(af[f], bfa, acc1[f][g], 0, 0, 0);
                acc2[f][g] = __builtin_amdgcn_mfma_f32_16x16x32_bf16(af[f], bfb, acc2[f][g], 0, 0, 0);
            }
        }
    }
#pragma unroll
    for (int g = 0; g < 2; ++g) {
        int colc = c0 + g * 16 + lr;
        float bb1 = b1[colc], bb2 = b2[colc];
        float asv = a_se[colc], anv = a_ne[colc];
        int h = (c0 >> 4) + g;
#pragma unroll
        for (int f = 0; f < 4; ++f)
#pragma unroll
            for (int i = 0; i < 4; ++i) {
                int row = r0 + f * 16 + lg * 4 + i;
                float o1 = fmaxf(acc1[f][g][i] + bb1, 0.f);  // hs (ephemeral)
                float o2 = fmaxf(acc2[f][g][i] + bb2, 0.f);  // hn
                if (row < NN) out2[(size_t)row * DD + colc] = (short)f2bf(o2);
                float ds = o1 * asv, dn = o1 * anv;
                ds += __shfl_xor(ds, 1);
                dn += __shfl_xor(dn, 1);
                ds += __shfl_xor(ds, 2);
                dn += __shfl_xor(dn, 2);
                ds += __shfl_xor(ds, 4);
                dn += __shfl_xor(dn, 4);
                ds += __shfl_xor(ds, 8);
                dn += __shfl_xor(dn, 8);
                if (lr == 0 && row < NN) {
                    ats_o[row * NH + h] = ds > 0.f ? ds : 0.2f * ds;
                    atn_o[row * NH + h] = dn > 0.f ? dn : 0.2f * dn;
                }
            }
    }
}

// ---------------- fused gather pass A: GAT-L0 + 3x GCN-L0 ----------------
// record: x = col | vg<<16, y = vu | vp<<16, z = vf

__global__ __launch_bounds__(256) void spmm_fusedA(
    const short* __restrict__ hnb, const short* __restrict__ fbf, const float* __restrict__ ats,
    const float* __restrict__ atn, const int4* __restrict__ ed, const int* __restrict__ row_ptr,
    float* __restrict__ aggG, short* __restrict__ zu, short* __restrict__ zp,
    short* __restrict__ zf, float* __restrict__ rs_all) {
    int r = __builtin_amdgcn_readfirstlane((blockIdx.x * 256 + threadIdx.x) >> 6);
    int lane = threadIdx.x & 63;
    if (r >= NN) return;
    int hh = lane >> 3;
    float a_s = ats[r * NH + hh];
    int start = row_ptr[r], end = row_ptr[r + 1];
    float2 ag = {0.f, 0.f}, au = {0.f, 0.f}, ap = {0.f, 0.f}, af2 = {0.f, 0.f};
    float su = 0.f, sp = 0.f, sf = 0.f;
    int j = start;
    for (; j + 2 <= end; j += 2) {
        int4 e0 = ed[j], e1 = ed[j + 1];
        int cA = e0.x & 0xffff, cB = e1.x & 0xffff;
        float at0 = atn[cA * NH + hh], at1 = atn[cB * NH + hh];
        unsigned int g0 = *(const unsigned int*)(hnb + (size_t)cA * DD + lane * 2);
        unsigned int f0 = *(const unsigned int*)(fbf + (size_t)cA * DD + lane * 2);
        unsigned int g1 = *(const unsigned int*)(hnb + (size_t)cB * DD + lane * 2);
        unsigned int f1 = *(const unsigned int*)(fbf + (size_t)cB * DD + lane * 2);
        {
            float vg = bfhi((unsigned)e0.x), vu = bflo((unsigned)e0.y);
            float vp = bfhi((unsigned)e0.y), vf = bflo((unsigned)e0.z);
            float e = (a_s + at0) * vg;
            float glo = bflo(g0), ghi = bfhi(g0), flo = bflo(f0), fhi = bfhi(f0);
            ag.x += e * glo;  ag.y += e * ghi;
            au.x += vu * flo; au.y += vu * fhi;
            ap.x += vp * flo; ap.y += vp * fhi;
            af2.x += vf * flo; af2.y += vf * fhi;
            su += vu; sp += vp; sf += vf;
        }
        {
            float vg = bfhi((unsigned)e1.x), vu = bflo((unsigned)e1.y);
            float vp = bfhi((unsigned)e1.y), vf = bflo((unsigned)e1.z);
            float e = (a_s + at1) * vg;
            float glo = bflo(g1), ghi = bfhi(g1), flo = bflo(f1), fhi = bfhi(f1);
            ag.x += e * glo;  ag.y += e * ghi;
            au.x += vu * flo; au.y += vu * fhi;
            ap.x += vp * flo; ap.y += vp * fhi;
            af2.x += vf * flo; af2.y += vf * fhi;
            su += vu; sp += vp; sf += vf;
        }
    }
    if (j < end) {
        int4 e0 = ed[j];
        int cA = e0.x & 0xffff;
        float at0 = atn[cA * NH + hh];
        unsigned int g0 = *(const unsigned int*)(hnb + (size_t)cA * DD + lane * 2);
        unsigned int f0 = *(const unsigned int*)(fbf + (size_t)cA * DD + lane * 2);
        float vg = bfhi((unsigned)e0.x), vu = bflo((unsigned)e0.y);
        float vp = bfhi((unsigned)e0.y), vf = bflo((unsigned)e0.z);
        float e = (a_s + at0) * vg;
        float glo = bflo(g0), ghi = bfhi(g0), flo = bflo(f0), fhi = bfhi(f0);
        ag.x += e * glo;  ag.y += e * ghi;
        au.x += vu * flo; au.y += vu * fhi;
        ap.x += vp * flo; ap.y += vp * fhi;
        af2.x += vf * flo; af2.y += vf * fhi;
        su += vu; sp += vp; sf += vf;
    }
    size_t o = (size_t)r * DD + lane * 2;
    *(float2*)&aggG[o] = ag;
    *(unsigned int*)(zu + o) = pack2bf(au.x, au.y);
    *(unsigned int*)(zp + o) = pack2bf(ap.x, ap.y);
    *(unsigned int*)(zf + o) = pack2bf(af2.x, af2.y);
    if (lane == 0) {
        rs_all[r] = su;
        rs_all[NN + r] = sp;
        rs_all[2 * NN + r] = sf;
    }
}

// ---------------- fused gather pass B: GAT-L1 + 3x GCN-L1 ----------------

__global__ __launch_bounds__(256) void spmm_fusedB(
    const short* __restrict__ hnb, const short* __restrict__ y0u, const short* __restrict__ y0p,
    const short* __restrict__ y0f, const float* __restrict__ ats, const float* __restrict__ atn,
    const int4* __restrict__ ed, const int* __restrict__ row_ptr, float* __restrict__ aggG,
    short* __restrict__ z1u, short* __restrict__ z1p, short* __restrict__ z1f) {
    int r = __builtin_amdgcn_readfirstlane((blockIdx.x * 256 + threadIdx.x) >> 6);
    int lane = threadIdx.x & 63;
    if (r >= NN) return;
    int hh = lane >> 3;
    float a_s = ats[r * NH + hh];
    int start = row_ptr[r], end = row_ptr[r + 1];
    float2 ag = {0.f, 0.f}, au = {0.f, 0.f}, ap = {0.f, 0.f}, af2 = {0.f, 0.f};
    int j = start;
    for (; j + 2 <= end; j += 2) {
        int4 e0 = ed[j], e1 = ed[j + 1];
        int cA = e0.x & 0xffff, cB = e1.x & 0xffff;
        float at0 = atn[cA * NH + hh], at1 = atn[cB * NH + hh];
        size_t oA = (size_t)cA * DD + lane * 2, oB = (size_t)cB * DD + lane * 2;
        unsigned int g0 = *(const unsigned int*)(hnb + oA);
        unsigned int u0 = *(const unsigned int*)(y0u + oA);
        unsigned int p0 = *(const unsigned int*)(y0p + oA);
        unsigned int q0 = *(const unsigned int*)(y0f + oA);
        unsigned int g1 = *(const unsigned int*)(hnb + oB);
        unsigned int u1 = *(const unsigned int*)(y0u + oB);
        unsigned int p1 = *(const unsigned int*)(y0p + oB);
        unsigned int q1 = *(const unsigned int*)(y0f + oB);
        float ea0 = (a_s + at0) * bfhi((unsigned)e0.x);
        float ea1 = (a_s + at1) * bfhi((unsigned)e1.x);
        float vu0 = bflo((unsigned)e0.y), vp0 = bfhi((unsigned)e0.y), vf0 = bflo((unsigned)e0.z);
        float vu1 = bflo((unsigned)e1.y), vp1 = bfhi((unsigned)e1.y), vf1 = bflo((unsigned)e1.z);
        ag.x += ea0 * bflo(g0) + ea1 * bflo(g1);
        ag.y += ea0 * bfhi(g0) + ea1 * bfhi(g1);
        au.x += vu0 * bflo(u0) + vu1 * bflo(u1);
        au.y += vu0 * bfhi(u0) + vu1 * bfhi(u1);
        ap.x += vp0 * bflo(p0) + vp1 * bflo(p1);
        ap.y += vp0 * bfhi(p0) + vp1 * bfhi(p1);
        af2.x += vf0 * bflo(q0) + vf1 * bflo(q1);
        af2.y += vf0 * bfhi(q0) + vf1 * bfhi(q1);
    }
    if (j < end) {
        int4 e0 = ed[j];
        int cA = e0.x & 0xffff;
        float at0 = atn[cA * NH + hh];
        size_t oA = (size_t)cA * DD + lane * 2;
        unsigned int g0 = *(const unsigned int*)(hnb + oA);
        unsigned int u0 = *(const unsigned int*)(y0u + oA);
        unsigned int p0 = *(const unsigned int*)(y0p + oA);
        unsigned int q0 = *(const unsigned int*)(y0f + oA);
        float ea0 = (a_s + at0) * bfhi((unsigned)e0.x);
        float vu0 = bflo((unsigned)e0.y), vp0 = bfhi((unsigned)e0.y), vf0 = bflo((unsigned)e0.z);
        ag.x += ea0 * bflo(g0);
        ag.y += ea0 * bfhi(g0);
        au.x += vu0 * bflo(u0);
        au.y += vu0 * bfhi(u0);
        ap.x += vp0 * bflo(p0);
        ap.y += vp0 * bfhi(p0);
        af2.x += vf0 * bflo(q0);
        af2.y += vf0 * bfhi(q0);
    }
    size_t o = (size_t)r * DD + lane * 2;
    *(float2*)&aggG[o] = ag;
    *(unsigned int*)(z1u + o) = pack2bf(au.x, au.y);
    *(unsigned int*)(z1p + o) = pack2bf(ap.x, ap.y);
    *(unsigned int*)(z1f + o) = pack2bf(af2.x, af2.y);
}

// ---------------- classifier (fp32 input + BN; GAT/self) ----------------

template <bool FIRST>
__global__ __launch_bounds__(256) void cls_acc_kernel(const float* __restrict__ o,
                                                      const float* __restrict__ Wc,
                                                      const float* __restrict__ stats,
                                                      const float* __restrict__ b_cls,
                                                      float* __restrict__ out) {
    __shared__ float Wl[DD * NCLS];
    __shared__ float mS[DD], sS[DD];
    int t = threadIdx.x;
    for (int i = t; i < DD * NCLS; i += 256) Wl[i] = Wc[i];
    if (t < DD) {
        const float inv_n = 1.0f / (float)NN;
        float m = stats[t] * inv_n;
        float var = stats[DD + t] * inv_n - m * m;
        mS[t] = m;
        sS[t] = rsqrtf(var + 1e-9f);
    }
    __syncthreads();
    int n = blockIdx.x * 256 + t;
    if (n >= NN) return;
    float acc[NCLS] = {};
    const float4* orow = (const float4*)(o + (size_t)n * DD);
    for (int k4 = 0; k4 < DD / 4; ++k4) {
        float4 v = orow[k4];
#pragma unroll
        for (int kk = 0; kk < 4; ++kk) {
            int k = k4 * 4 + kk;
            float a = (((const float*)&v)[kk] - mS[k]) * sS[k];
#pragma unroll
            for (int c = 0; c < NCLS; ++c) acc[c] += a * Wl[k * NCLS + c];
        }
    }
#pragma unroll
    for (int c = 0; c < NCLS; ++c) {
        if (FIRST)
            out[n * NCLS + c] = acc[c] + b_cls[c];
        else
            out[n * NCLS + c] += acc[c];
    }
}

// ---- batched GCN classifier (bf16 y1, BN via stats; atomic accumulate) ----

struct CLS3 {
    const short* o[3];
    const float* stats[3];
};

__global__ __launch_bounds__(256) void cls3_kernel(CLS3 a, const float* __restrict__ W_cls,
                                                   float* __restrict__ out) {
    int br = blockIdx.y;
    const short* o = a.o[br];
    const float* st = a.stats[br];
    const float* Wc = W_cls + (size_t)(DD + DD * br) * NCLS;
    __shared__ float Wl[DD * NCLS];
    __shared__ float mS[DD], sS[DD];
    int t = threadIdx.x;
    for (int i = t; i < DD * NCLS; i += 256) Wl[i] = Wc[i];
    if (t < DD) {
        const float inv_n = 1.0f / (float)NN;
        float m = st[t] * inv_n;
        float var = st[DD + t] * inv_n - m * m;
        mS[t] = m;
        sS[t] = rsqrtf(var + 1e-9f);
    }
    __syncthreads();
    int n = blockIdx.x * 256 + t;
    if (n >= NN) return;
    float acc[NCLS] = {};
    const uint4* orow = (const uint4*)(o + (size_t)n * DD);
    for (int k8 = 0; k8 < DD / 8; ++k8) {
        uint4 v = orow[k8];
        float vv[8] = {bflo(v.x), bfhi(v.x), bflo(v.y), bfhi(v.y),
                       bflo(v.z), bfhi(v.z), bflo(v.w), bfhi(v.w)};
#pragma unroll
        for (int kk = 0; kk < 8; ++kk) {
            int k = k8 * 8 + kk;
            float a2 = (vv[kk] - mS[k]) * sS[k];
#pragma unroll
            for (int c = 0; c < NCLS; ++c) acc[c] += a2 * Wl[k * NCLS + c];
        }
    }
#pragma unroll
    for (int c = 0; c < NCLS; ++c) atomicAdd(&out[n * NCLS + c], acc[c]);
}

// ---------------------------------------------------------------------------

extern "C" void kernel_launch(void* const* d_in, const int* in_sizes, int n_in, void* d_out,
                              int out_size, void* d_ws, size_t ws_size, hipStream_t stream) {
    const float* f_in = (const float*)d_in[0];
    const int* edge_row = (const int*)d_in[1];
    const int* edge_col = (const int*)d_in[2];
    const float* vals_gat = (const float*)d_in[3];
    const float* vals_uttr = (const float*)d_in[4];
    const float* vals_past = (const float*)d_in[5];
    const float* vals_futr = (const float*)d_in[6];
    const float* gat_Ws = (const float*)d_in[7];
    const float* gat_bs = (const float*)d_in[8];
    const float* gat_Wn = (const float*)d_in[9];
    const float* gat_bn = (const float*)d_in[10];
    const float* gat_as = (const float*)d_in[11];
    const float* gat_an = (const float*)d_in[12];
    const float* W_uttr = (const float*)d_in[13];
    const float* b_uttr = (const float*)d_in[14];
    const float* W_past = (const float*)d_in[15];
    const float* b_past = (const float*)d_in[16];
    const float* W_futr = (const float*)d_in[17];
    const float* b_futr = (const float*)d_in[18];
    const float* W_self = (const float*)d_in[19];
    const float* b_self = (const float*)d_in[20];
    const float* W_cls = (const float*)d_in[21];
    const float* b_cls = (const float*)d_in[22];
    float* out = (float*)d_out;

    char* ws = (char*)d_ws;
    size_t off = 0;
    auto alloc = [&](size_t bytes) -> void* {
        void* p = ws + off;
        off = (off + bytes + 255) & ~(size_t)255;
        return p;
    };
    float* stats_all = (float*)alloc(9 * 2 * DD * 4);
    int* cnt = (int*)alloc((size_t)NN * 4);  // adjacent to stats -> one memset
    float* tmp1 = (float*)alloc((size_t)NN * DD * 4);  // self h; later z1p/z1f
    float* bufA = (float*)alloc((size_t)NN * DD * 4);  // GAT agg L0/L1
    short* fbf = (short*)alloc((size_t)NN * DD * 2);   // f_in bf16; later z1u
    short* hnb = (short*)alloc((size_t)NN * DD * 2);   // GAT hn L0/L1
    short* z0u = (short*)alloc((size_t)NN * DD * 2);   // z0 -> y0 (in-place) -> y1
    short* z0p = (short*)alloc((size_t)NN * DD * 2);
    short* z0f = (short*)alloc((size_t)NN * DD * 2);
    float* rs_all = (float*)alloc((size_t)3 * NN * 4);
    float* ats_b = (float*)alloc((size_t)NN * NH * 4);
    float* atn_b = (float*)alloc((size_t)NN * NH * 4);
    short* Wt_all = (short*)alloc((size_t)14 * DD * DD * 2);
    float* bfix = (float*)alloc((size_t)3 * DD * 4);
    int* row_ptr = (int*)alloc((size_t)(NN + 1) * 4);
    int* fill = (int*)alloc((size_t)NN * 4);
    int* pre_b = (int*)alloc((size_t)NN * 4);
    int* bsum = (int*)alloc((size_t)SCAN_B * 4);
    int* boff = (int*)alloc((size_t)257 * 4);
    int4* ed = (int4*)alloc((size_t)NE * 16);

    auto stats = [&](int s) { return stats_all + (size_t)s * 2 * DD; };
    auto Wt = [&](int w) { return Wt_all + (size_t)w * DD * DD; };
    // stats: 0=GAT L0 agg, 1=GAT L1 agg, 2..4=GCN y0, 5..7=GCN y1, 8=self

    const int gE = (NE + 255) / 256;
    const int gMM = (NN + 63) / 64;
    const int gSP = NN / 4;  // exact (NN % 4 == 0)
    const int gCA = (NN + 255) / 256;
    const int gBF = (NN * DD / 8 + 255) / 256;

    hipMemsetAsync(stats_all, 0, 9 * 2 * DD * 4 + (size_t)NN * 4, stream);

    // CSR build
    count_kernel<<<gE, 256, 0, stream>>>(edge_row, cnt);
    scan1_kernel<<<SCAN_B, 256, 0, stream>>>(cnt, pre_b, bsum);
    scan2_kernel<<<1, 256, 0, stream>>>(bsum, boff);
    scan3_kernel<<<SCAN_B, 256, 0, stream>>>(pre_b, boff, row_ptr, fill);
    scatter_kernel<<<gE, 256, 0, stream>>>(edge_row, edge_col, vals_gat, vals_uttr, vals_past,
                                           vals_futr, fill, ed);

    tobf16_kernel<<<gBF, 256, 0, stream>>>(f_in, fbf);

    WPrepArgs wa;
    wa.src[0] = gat_Ws;
    wa.src[1] = gat_Wn;
    wa.src[2] = gat_Ws + (size_t)DD * DD;
    wa.src[3] = gat_Wn + (size_t)DD * DD;
    wa.src[4] = W_uttr;
    wa.src[5] = W_uttr + (size_t)DD * DD;  // unused slot
    wa.src[6] = W_past;
    wa.src[7] = W_past + (size_t)DD * DD;  // unused slot
    wa.src[8] = W_futr;
    wa.src[9] = W_futr + (size_t)DD * DD;  // unused slot
    wa.src[10] = W_self;
    wprep_kernel<<<(11 * DD * DD + 255) / 256, 256, 0, stream>>>(wa, Wt_all);

    // ---- self branch (FIRST classifier write) ----
    mfma_mm_self<<<gMM, 256, 0, stream>>>(fbf, Wt(10), b_self, stats(8), tmp1);
    cls_acc_kernel<true><<<gCA, 256, 0, stream>>>(tmp1, W_cls + (size_t)4 * DD * NCLS, stats(8),
                                                  b_cls, out);

    // ---- GAT L0 + fused gather A (also GCN L0 z) ----
    mfma_mm_pair<0><<<gMM, 256, 0, stream>>>(fbf, Wt(0), Wt(1), gat_bs, gat_bn, gat_as, gat_an,
                                             nullptr, hnb, ats_b, atn_b);
    spmm_fusedA<<<gSP, 256, 0, stream>>>(hnb, fbf, ats_b, atn_b, ed, row_ptr, bufA, z0u, z0p,
                                         z0f, rs_all);
    bn_stats_kernel<<<256, 256, 0, stream>>>(bufA, stats(0));

    // ---- GAT L1 matmul (BN on the fly) ----
    mfma_mm_pair<1><<<gMM, 256, 0, stream>>>(bufA, Wt(2), Wt(3), gat_bs + DD, gat_bn + DD,
                                             gat_as + DD, gat_an + DD, stats(0), hnb, ats_b,
                                             atn_b);

    // ---- GCN L0 matmuls (batched, in-place z0 -> y0 bf16, stats 2..4) ----
    const float* bb[3] = {b_uttr, b_past, b_futr};
    const float* Worig[3] = {W_uttr, W_past, W_futr};
    MMB m0;
    short* z0a[3] = {z0u, z0p, z0f};
    for (int br = 0; br < 3; ++br) {
        m0.A[br] = z0a[br];
        m0.W[br] = Wt(4 + br * 2);
        m0.bias[br] = bb[br];
        m0.rs[br] = rs_all + (size_t)br * NN;
        m0.stats[br] = stats(2 + br);
        m0.C[br] = z0a[br];
    }
    mfma_mm_gcn<<<dim3(gMM, 3), 256, 0, stream>>>(m0);

    // ---- wfix: fold BN(y0) into L1 weights ----
    WFixArgs wf;
    for (int br = 0; br < 3; ++br) {
        wf.W1[br] = Worig[br] + (size_t)DD * DD;
        wf.b1[br] = bb[br] + DD;
        wf.stats[br] = stats(2 + br);
    }
    wfix_kernel<<<2, 256, 0, stream>>>(wf, Wt(11), bfix);

    // ---- fused gather B: GAT-L1 agg + 3x GCN z1 ----
    short* z1u = fbf;           // fbf dead
    short* z1p = (short*)tmp1;  // tmp1 dead after self cls
    short* z1f = (short*)tmp1 + (size_t)NN * DD;
    spmm_fusedB<<<gSP, 256, 0, stream>>>(hnb, z0u, z0p, z0f, ats_b, atn_b, ed, row_ptr, bufA,
                                         z1u, z1p, z1f);
    bn_stats_kernel<<<256, 256, 0, stream>>>(bufA, stats(1));
    cls_acc_kernel<false><<<gCA, 256, 0, stream>>>(bufA, W_cls, stats(1), b_cls, out);

    // ---- GCN L1 matmuls (batched, z1 -> y1 bf16 into z0 slots, stats 5..7) ----
    MMB m1;
    short* z1a[3] = {z1u, z1p, z1f};
    for (int br = 0; br < 3; ++br) {
        m1.A[br] = z1a[br];
        m1.W[br] = Wt(11 + br);
        m1.bias[br] = bfix + (size_t)br * DD;
        m1.rs[br] = rs_all + (size_t)br * NN;
        m1.stats[br] = stats(5 + br);
        m1.C[br] = z0a[br];
    }
    mfma_mm_gcn<<<dim3(gMM, 3), 256, 0, stream>>>(m1);

    // ---- batched GCN classifiers ----
    CLS3 c3;
    for (int br = 0; br < 3; ++br) {
        c3.o[br] = z0a[br];
        c3.stats[br] = stats(5 + br);
    }
    cls3_kernel<<<dim3(gCA, 3), 256, 0, stream>>>(c3, W_cls, out);
}